// Round 3
// baseline (931.984 us; speedup 1.0000x reference)
//
#include <hip/hip_runtime.h>

#define LRELU(x) ((x) > 0.f ? (x) : 0.2f * (x))

// ---------------- small helpers ----------------

__global__ void zero3_k(int* __restrict__ a, int* __restrict__ b,
                        float* __restrict__ c, int n) {
  int i = blockIdx.x * 256 + threadIdx.x;
  if (i < n) { a[i] = 0; b[i] = 0; c[i] = 0.f; }
}

// sw[0..2] = We1^T @ ae1 per edge-dim row; sw[3] = We2 . ae2; sw[4] = We3 . ae3
__global__ void small_weights_k(const float* __restrict__ We1, const float* __restrict__ ae1,
                                const float* __restrict__ We2, const float* __restrict__ ae2,
                                const float* __restrict__ We3, const float* __restrict__ ae3,
                                float* __restrict__ sw) {
  int t = threadIdx.x;  // 64 threads = 1 wave
  float v0 = We1[t] * ae1[t];
  float v1 = We1[64 + t] * ae1[t];
  float v2 = We1[128 + t] * ae1[t];
  float v3 = We2[t] * ae2[t];
  float v4 = (t < 32) ? We3[t] * ae3[t] : 0.f;
#pragma unroll
  for (int off = 32; off > 0; off >>= 1) {
    v0 += __shfl_down(v0, off);
    v1 += __shfl_down(v1, off);
    v2 += __shfl_down(v2, off);
    v3 += __shfl_down(v3, off);
    v4 += __shfl_down(v4, off);
  }
  if (t == 0) { sw[0] = v0; sw[1] = v1; sw[2] = v2; sw[3] = v3; sw[4] = v4; }
}

__global__ void count_deg_k(const int* __restrict__ dst, int* __restrict__ deg, int E) {
  int i = blockIdx.x * 256 + threadIdx.x;
  if (i < E) atomicAdd(&deg[dst[i]], 1);
}

// ---------------- exclusive scan (rowptr) ----------------

__global__ void scan1_k(const int* __restrict__ deg, int* __restrict__ rowptr,
                        int* __restrict__ bsum, int n) {
  __shared__ int s[1024];
  int t = threadIdx.x, i = blockIdx.x * 1024 + t;
  int v = (i < n) ? deg[i] : 0;
  s[t] = v;
  __syncthreads();
  for (int off = 1; off < 1024; off <<= 1) {
    int add = (t >= off) ? s[t - off] : 0;
    __syncthreads();
    s[t] += add;
    __syncthreads();
  }
  if (i < n) rowptr[i + 1] = s[t];
  if (t == 1023) bsum[blockIdx.x] = s[t];
}

__global__ void scan2_k(const int* __restrict__ bsum, int* __restrict__ boff, int nb) {
  if (threadIdx.x == 0) {
    int acc = 0;
    for (int b = 0; b < nb; b++) { boff[b] = acc; acc += bsum[b]; }
  }
}

__global__ void scan3_k(int* __restrict__ rowptr, const int* __restrict__ boff, int n) {
  int i = blockIdx.x * 256 + threadIdx.x;
  if (i < n) rowptr[i + 1] += boff[i / 1024];
  if (i == 0) rowptr[0] = 0;
}

// ---------------- CSR scatter, fused with layer-1 edge exp ----------------
// Writes ONE packed int2 (src, exp(lrelu(logit))) per edge; also accumulates
// per-dst raw attr sum (for the self-loop mean) via atomics.

__global__ void scatter_k(const int* __restrict__ src, const int* __restrict__ dst,
                          const float* __restrict__ eattr, const int* __restrict__ rowptr,
                          int* __restrict__ fill, const float* __restrict__ asrc,
                          const float* __restrict__ adst, float* __restrict__ asum,
                          int2* __restrict__ edge, const float* __restrict__ sw, int E) {
  int e = blockIdx.x * 256 + threadIdx.x;
  if (e >= E) return;
  int sv = src[e], d = dst[e];
  float ae = eattr[e * 3] * sw[0] + eattr[e * 3 + 1] * sw[1] + eattr[e * 3 + 2] * sw[2];
  float ex = __expf(LRELU(asrc[sv] + adst[d] + ae));
  atomicAdd(&asum[d], ae);
  int pos = rowptr[d] + atomicAdd(&fill[d], 1);
  int2 pk;
  pk.x = sv;
  pk.y = __float_as_int(ex);
  edge[pos] = pk;
}

// ---------------- layer-1 GEMM: x [n,5] @ W [5,64] (wave per node) -------------

__global__ void gemm1_k(const float* __restrict__ x, const float* __restrict__ W,
                        const float* __restrict__ as, const float* __restrict__ ad,
                        float* __restrict__ h, float* __restrict__ asrc,
                        float* __restrict__ adst, int n) {
  int lane = threadIdx.x & 63;
  int v = (blockIdx.x * blockDim.x + threadIdx.x) >> 6;
  if (v >= n) return;
  float acc = 0.f;
#pragma unroll
  for (int k = 0; k < 5; k++) acc += x[v * 5 + k] * W[k * 64 + lane];
  h[(size_t)v * 64 + lane] = acc;
  float ps = acc * as[lane], pd = acc * ad[lane];
#pragma unroll
  for (int off = 32; off > 0; off >>= 1) {
    ps += __shfl_down(ps, off);
    pd += __shfl_down(pd, off);
  }
  if (lane == 0) { asrc[v] = ps; adst[v] = pd; }
}

// ---------------- tiled GEMM: x [n,64] @ W [64,C], 4x4 register blocking -------

template <int C>
__global__ __launch_bounds__(256) void gemm_tile_k(
    const float* __restrict__ x, const float* __restrict__ W,
    const float* __restrict__ as, const float* __restrict__ ad,
    float* __restrict__ h, float* __restrict__ asrc, float* __restrict__ adst, int n) {
  constexpr int NT = 4096 / C;   // nodes per block: 64 (C=64) / 128 (C=32)
  constexpr int CG = C / 4;      // channel groups: 16 / 8
  constexpr int XTP = NT + 4;    // pad keeps float4 alignment
  __shared__ float XT[64][XTP];  // transposed x tile: XT[k][node]
  __shared__ float Wl[64 * C];
  const int t = threadIdx.x;
  const int v0 = blockIdx.x * NT;
  for (int i = t; i < 64 * C; i += 256) Wl[i] = W[i];
  for (int i = t; i < NT * 64; i += 256) {
    int node = i >> 6, k = i & 63;
    int v = v0 + node;
    XT[k][node] = (v < n) ? x[(size_t)v * 64 + k] : 0.f;
  }
  __syncthreads();
  const int cg = t % CG, ng = t / CG;
  const int c0 = cg * 4, n0 = ng * 4;
  float acc[4][4] = {};
#pragma unroll 4
  for (int k = 0; k < 64; ++k) {
    const float4 xv = *(const float4*)&XT[k][n0];
    const float4 wv = *(const float4*)&Wl[k * C + c0];
    acc[0][0] += xv.x * wv.x; acc[0][1] += xv.x * wv.y; acc[0][2] += xv.x * wv.z; acc[0][3] += xv.x * wv.w;
    acc[1][0] += xv.y * wv.x; acc[1][1] += xv.y * wv.y; acc[1][2] += xv.y * wv.z; acc[1][3] += xv.y * wv.w;
    acc[2][0] += xv.z * wv.x; acc[2][1] += xv.z * wv.y; acc[2][2] += xv.z * wv.z; acc[2][3] += xv.z * wv.w;
    acc[3][0] += xv.w * wv.x; acc[3][1] += xv.w * wv.y; acc[3][2] += xv.w * wv.z; acc[3][3] += xv.w * wv.w;
  }
  float asv[4] = {as[c0], as[c0 + 1], as[c0 + 2], as[c0 + 3]};
  float adv[4] = {ad[c0], ad[c0 + 1], ad[c0 + 2], ad[c0 + 3]};
  float ps[4], pd[4];
#pragma unroll
  for (int ni = 0; ni < 4; ++ni) {
    ps[ni] = acc[ni][0] * asv[0] + acc[ni][1] * asv[1] + acc[ni][2] * asv[2] + acc[ni][3] * asv[3];
    pd[ni] = acc[ni][0] * adv[0] + acc[ni][1] * adv[1] + acc[ni][2] * adv[2] + acc[ni][3] * adv[3];
  }
#pragma unroll
  for (int off = CG / 2; off > 0; off >>= 1) {
#pragma unroll
    for (int ni = 0; ni < 4; ++ni) {
      ps[ni] += __shfl_xor(ps[ni], off);
      pd[ni] += __shfl_xor(pd[ni], off);
    }
  }
#pragma unroll
  for (int ni = 0; ni < 4; ++ni) {
    int v = v0 + n0 + ni;
    if (v < n) {
      float4 o = make_float4(acc[ni][0], acc[ni][1], acc[ni][2], acc[ni][3]);
      *(float4*)&h[(size_t)v * C + c0] = o;
      if (cg == 0) { asrc[v] = ps[ni]; adst[v] = pd[ni]; }
    }
  }
}

// ---------------- per-node softmax + aggregate ----------------
// edge[p] = (src, ex). LAYER=1: ex precomputed by scatter (read-only here);
// raw attr sum comes from asum[]. LAYER>=2: ex field holds PREV layer's
// unnormalized ex; pass A replaces it in place with this layer's ex.
// Deferred normalization: oinv[v]=1/denom folded into next layer via pinv.
// C=64: 1 node/wave. C=32: 2 nodes/wave.
template <int LAYER, int C>
__global__ __launch_bounds__(256) void agg_k(
    const int* __restrict__ rowptr, int2* __restrict__ edge,
    const float* __restrict__ h, const float* __restrict__ asrc,
    const float* __restrict__ adst, const float* __restrict__ asum,
    const float* __restrict__ pinv, const float* __restrict__ lp1,
    const float* __restrict__ lp2, float* __restrict__ oinv,
    float* __restrict__ ol1, float* __restrict__ ol2,
    const float* __restrict__ sw, const float* __restrict__ bias,
    float* __restrict__ out, int n) {
  constexpr int L = (C == 64) ? 64 : 32;  // lanes per node
  const int lane = threadIdx.x & 63;
  const int ln = lane & (L - 1);
  const int wid = (blockIdx.x * blockDim.x + threadIdx.x) >> 6;
  const int v = (C == 64) ? wid : wid * 2 + (lane >> 5);
  if (v >= n) return;
  const float s = (LAYER == 1) ? 1.f : (LAYER == 2 ? sw[3] : sw[4]);
  const float fac = (LAYER == 1) ? 1.f : pinv[v];
  const float sf = s * fac;
  const int r0 = rowptr[v], r1 = rowptr[v + 1];
  const float av_d = adst[v], av_s = asrc[v];

  // pass A (lane-parallel)
  float rawsum = 0.f, den = 0.f;
  if (LAYER == 1) {
    for (int p = r0 + ln; p < r1; p += L) den += __int_as_float(edge[p].y);
  } else {
    for (int p = r0 + ln; p < r1; p += L) {
      int2 pk = edge[p];
      float a = __int_as_float(pk.y);
      rawsum += a;
      float lg = asrc[pk.x] + av_d + sf * a;
      float ex = __expf(LRELU(lg));
      edge[p].y = __float_as_int(ex);
      den += ex;
    }
    __threadfence_block();
  }
#pragma unroll
  for (int off = L / 2; off > 0; off >>= 1) {
    den += __shfl_xor(den, off);
    if (LAYER >= 2) rawsum += __shfl_xor(rawsum, off);
  }
  const float base = av_s + av_d;
  float la1 = 0.f, la2 = 0.f, e1 = 0.f, e2 = 0.f;
  if (LAYER >= 2) { la1 = fac * lp1[v]; e1 = __expf(LRELU(base + s * la1)); den += e1; }
  if (LAYER >= 3) { la2 = fac * lp2[v]; e2 = __expf(LRELU(base + s * la2)); den += e2; }
  int dd = (r1 - r0) + (LAYER - 1);
  if (dd < 1) dd = 1;
  float sum_a = (LAYER == 1) ? asum[v] : fac * rawsum + la1 + la2;
  float lmean = sum_a / (float)dd;
  float exm = __expf(LRELU(base + s * lmean));
  den += exm;
  float inv = 1.f / (den + 1e-16f);
  if (ln == 0) {
    if (LAYER < 3) oinv[v] = inv;
    if (LAYER == 1) ol1[v] = exm;
    if (LAYER == 2) { ol1[v] = e1; ol2[v] = exm; }
  }

  // pass B (serial over edges, lane = channel, 4-deep ILP)
  const int c = ln;
  const float* __restrict__ hc = h + c;
  float a0 = 0.f, a1 = 0.f, a2 = 0.f, a3 = 0.f;
  int p = r0;
  for (; p + 4 <= r1; p += 4) {
    int2 k0 = edge[p], k1 = edge[p + 1], k2 = edge[p + 2], k3 = edge[p + 3];
    a0 += __int_as_float(k0.y) * hc[(size_t)k0.x * C];
    a1 += __int_as_float(k1.y) * hc[(size_t)k1.x * C];
    a2 += __int_as_float(k2.y) * hc[(size_t)k2.x * C];
    a3 += __int_as_float(k3.y) * hc[(size_t)k3.x * C];
  }
  for (; p < r1; ++p) a0 += __int_as_float(edge[p].y) * hc[(size_t)edge[p].x * C];
  float hv = hc[(size_t)v * C];
  float acc = (a0 + a1) + (a2 + a3) + (e1 + e2 + exm) * hv;
  float o = acc * inv + bias[c];
  if (LAYER < 3) o = fmaxf(o, 0.f);
  out[(size_t)v * C + c] = o;
}

// ---------------- global mean pool (block per graph) ----------------

__global__ void pool_k(const float* __restrict__ h, const int* __restrict__ batch,
                       float* __restrict__ out, int n) {
  int g = blockIdx.x;
  int lo = 0, hi = n;
  while (lo < hi) { int m = (lo + hi) >> 1; if (batch[m] < g) lo = m + 1; else hi = m; }
  int start = lo;
  hi = n;
  while (lo < hi) { int m = (lo + hi) >> 1; if (batch[m] < g + 1) lo = m + 1; else hi = m; }
  int end = lo;
  int t = threadIdx.x;
  int c = t & 31, r = t >> 5;
  float acc = 0.f;
  for (int v = start + r; v < end; v += 8) acc += h[(size_t)v * 32 + c];
  __shared__ float s[256];
  s[t] = acc;
  __syncthreads();
  if (t < 128) s[t] += s[t + 128];
  __syncthreads();
  if (t < 64) s[t] += s[t + 64];
  __syncthreads();
  if (t < 32) {
    float tot = s[t] + s[t + 32];
    int cnt = end - start;
    out[g * 32 + t] = tot / (float)(cnt > 0 ? cnt : 1);
  }
}

// ---------------- launch ----------------

extern "C" void kernel_launch(void* const* d_in, const int* in_sizes, int n_in,
                              void* d_out, int out_size, void* d_ws, size_t ws_size,
                              hipStream_t stream) {
  const float* x     = (const float*)d_in[0];
  const int*   ei    = (const int*)d_in[1];
  const float* eattr = (const float*)d_in[2];
  const int*   batch = (const int*)d_in[3];
  const float *W1 = (const float*)d_in[4],  *as1 = (const float*)d_in[5],
              *ad1 = (const float*)d_in[6], *We1 = (const float*)d_in[7],
              *ae1 = (const float*)d_in[8], *b1  = (const float*)d_in[9];
  const float *W2 = (const float*)d_in[10], *as2 = (const float*)d_in[11],
              *ad2 = (const float*)d_in[12], *We2 = (const float*)d_in[13],
              *ae2 = (const float*)d_in[14], *b2  = (const float*)d_in[15];
  const float *W3 = (const float*)d_in[16], *as3 = (const float*)d_in[17],
              *ad3 = (const float*)d_in[18], *We3 = (const float*)d_in[19],
              *ae3 = (const float*)d_in[20], *b3  = (const float*)d_in[21];

  const int n = in_sizes[3];
  const int E = in_sizes[1] / 2;
  const int G = out_size / 32;
  const int* srcp = ei;
  const int* dstp = ei + E;

  char* w = (char*)d_ws;
  auto alloc = [&](size_t bytes) -> void* {
    void* p = (void*)w;
    w += (bytes + 255) & ~(size_t)255;
    return p;
  };
  int*   deg     = (int*)alloc((size_t)n * 4);
  int*   fill    = (int*)alloc((size_t)n * 4);
  int*   rowptr  = (int*)alloc((size_t)(n + 1) * 4);
  int*   bsum    = (int*)alloc(1024);
  int*   boff    = (int*)alloc(1024);
  int2*  edge    = (int2*)alloc((size_t)E * 8);
  float* asum    = (float*)alloc((size_t)n * 4);
  float* H       = (float*)alloc((size_t)n * 64 * 4);
  float* O       = (float*)alloc((size_t)n * 64 * 4);
  float* asrcB   = (float*)alloc((size_t)n * 4);
  float* adstB   = (float*)alloc((size_t)n * 4);
  float* loopA   = (float*)alloc((size_t)n * 4);
  float* loopB1  = (float*)alloc((size_t)n * 4);
  float* loopB2  = (float*)alloc((size_t)n * 4);
  float* invA    = (float*)alloc((size_t)n * 4);
  float* invB    = (float*)alloc((size_t)n * 4);
  float* sw      = (float*)alloc(256);

  const int nb = (n + 1023) / 1024;
  dim3 blk256(256);
  dim3 gN((n + 255) / 256);
  dim3 gE((E + 255) / 256);
  dim3 gWave((n + 3) / 4);                 // wave per node
  const int nw3 = (n + 1) / 2;             // 2 nodes per wave (layer 3)
  dim3 gWave3((nw3 + 3) / 4);

  zero3_k<<<gN, blk256, 0, stream>>>(deg, fill, asum, n);
  small_weights_k<<<1, 64, 0, stream>>>(We1, ae1, We2, ae2, We3, ae3, sw);
  count_deg_k<<<gE, blk256, 0, stream>>>(dstp, deg, E);
  scan1_k<<<nb, 1024, 0, stream>>>(deg, rowptr, bsum, n);
  scan2_k<<<1, 64, 0, stream>>>(bsum, boff, nb);
  scan3_k<<<gN, blk256, 0, stream>>>(rowptr, boff, n);

  // layer 1 (gemm1 first: scatter consumes asrc/adst and emits layer-1 ex)
  gemm1_k<<<gWave, blk256, 0, stream>>>(x, W1, as1, ad1, H, asrcB, adstB, n);
  scatter_k<<<gE, blk256, 0, stream>>>(srcp, dstp, eattr, rowptr, fill,
                                       asrcB, adstB, asum, edge, sw, E);
  agg_k<1, 64><<<gWave, blk256, 0, stream>>>(rowptr, edge, H, asrcB, adstB, asum,
                                             nullptr, nullptr, nullptr,
                                             invA, loopA, nullptr, sw, b1, O, n);
  // layer 2
  gemm_tile_k<64><<<dim3((n + 63) / 64), blk256, 0, stream>>>(O, W2, as2, ad2, H, asrcB, adstB, n);
  agg_k<2, 64><<<gWave, blk256, 0, stream>>>(rowptr, edge, H, asrcB, adstB, nullptr,
                                             invA, loopA, nullptr,
                                             invB, loopB1, loopB2, sw, b2, O, n);
  // layer 3
  gemm_tile_k<32><<<dim3((n + 127) / 128), blk256, 0, stream>>>(O, W3, as3, ad3, H, asrcB, adstB, n);
  agg_k<3, 32><<<gWave3, blk256, 0, stream>>>(rowptr, edge, H, asrcB, adstB, nullptr,
                                              invB, loopB1, loopB2,
                                              nullptr, nullptr, nullptr, sw, b3, O, n);
  // pool
  pool_k<<<G, blk256, 0, stream>>>(O, batch, (float*)d_out, n);
}

// Round 4
// 930.249 us; speedup vs baseline: 1.0019x; 1.0019x over previous
//
#include <hip/hip_runtime.h>

#define LRELU(x) ((x) > 0.f ? (x) : 0.2f * (x))
#define BSH 6  // 64 nodes per bucket

// ---------------- small helpers ----------------

__global__ void zero_cnt_k(int* __restrict__ a, int* __restrict__ b, int m) {
  int i = blockIdx.x * 256 + threadIdx.x;
  if (i < m) { a[i] = 0; b[i] = 0; }
}

// sw[0..2] = We1^T @ ae1 per edge-dim row; sw[3] = We2 . ae2; sw[4] = We3 . ae3
__global__ void small_weights_k(const float* __restrict__ We1, const float* __restrict__ ae1,
                                const float* __restrict__ We2, const float* __restrict__ ae2,
                                const float* __restrict__ We3, const float* __restrict__ ae3,
                                float* __restrict__ sw) {
  int t = threadIdx.x;  // 64 threads = 1 wave
  float v0 = We1[t] * ae1[t];
  float v1 = We1[64 + t] * ae1[t];
  float v2 = We1[128 + t] * ae1[t];
  float v3 = We2[t] * ae2[t];
  float v4 = (t < 32) ? We3[t] * ae3[t] : 0.f;
#pragma unroll
  for (int off = 32; off > 0; off >>= 1) {
    v0 += __shfl_down(v0, off);
    v1 += __shfl_down(v1, off);
    v2 += __shfl_down(v2, off);
    v3 += __shfl_down(v3, off);
    v4 += __shfl_down(v4, off);
  }
  if (t == 0) { sw[0] = v0; sw[1] = v1; sw[2] = v2; sw[3] = v3; sw[4] = v4; }
}

// ---------------- bucketed CSR build ----------------
// S1: count per (bucket, replica=blockIdx&7)

__global__ void count_rep_k(const int* __restrict__ dst, int* __restrict__ cnt, int E) {
  int e = blockIdx.x * 256 + threadIdx.x;
  if (e >= E) return;
  int b = dst[e] >> BSH;
  atomicAdd(&cnt[b * 8 + (blockIdx.x & 7)], 1);
}

// S2: exclusive scan over m = B*8 counters (one block, 1024 threads); rbase[m] = total
__global__ void scan_rep_k(const int* __restrict__ cnt, int* __restrict__ rbase,
                           int* __restrict__ rowptr, int m) {
  __shared__ int part[1024];
  int t = threadIdx.x;
  int per = (m + 1023) / 1024;
  int s0 = t * per;
  int e0 = s0 + per;
  if (s0 > m) s0 = m;
  if (e0 > m) e0 = m;
  int sum = 0;
  for (int i = s0; i < e0; ++i) sum += cnt[i];
  part[t] = sum;
  __syncthreads();
  for (int off = 1; off < 1024; off <<= 1) {
    int add = (t >= off) ? part[t - off] : 0;
    __syncthreads();
    part[t] += add;
    __syncthreads();
  }
  int excl = (t == 0) ? 0 : part[t - 1];
  for (int i = s0; i < e0; ++i) {
    rbase[i] = excl;
    excl += cnt[i];
  }
  if (t == 1023) rbase[m] = part[1023];
  if (t == 0) rowptr[0] = 0;
}

// S3: append (dst,src) + folded edge-attr scalar into replica segments
__global__ void append_rep_k(const int* __restrict__ src, const int* __restrict__ dst,
                             const float* __restrict__ eattr, const int* __restrict__ rbase,
                             int* __restrict__ fillrep, int2* __restrict__ recDS,
                             float* __restrict__ recA, const float* __restrict__ sw, int E) {
  int e = blockIdx.x * 256 + threadIdx.x;
  if (e >= E) return;
  int d = dst[e];
  int idx = (d >> BSH) * 8 + (blockIdx.x & 7);
  float ae = eattr[e * 3] * sw[0] + eattr[e * 3 + 1] * sw[1] + eattr[e * 3 + 2] * sw[2];
  int pos = rbase[idx] + atomicAdd(&fillrep[idx], 1);
  recDS[pos] = make_int2(d, src[e]);
  recA[pos] = ae;
}

// S4: per-bucket compaction -> final CSR edge[] (src, layer-1 ex), rowptr, asum
__global__ __launch_bounds__(256) void bucket_build_k(
    const int2* __restrict__ recDS, const float* __restrict__ recA,
    const int* __restrict__ rbase, const float* __restrict__ asrc,
    const float* __restrict__ adst, int* __restrict__ rowptr,
    float* __restrict__ asum, int2* __restrict__ edge, int n) {
  __shared__ int cnt64[64];
  __shared__ int off64[64];
  __shared__ int fill64[64];
  __shared__ float rs[64];
  __shared__ float adl[64];
  const int b = blockIdx.x;
  const int t = threadIdx.x;
  const int v0 = b << BSH;
  const int nloc = min(64, n - v0);
  if (t < 64) {
    cnt64[t] = 0; fill64[t] = 0; rs[t] = 0.f;
    adl[t] = (t < nloc) ? adst[v0 + t] : 0.f;
  }
  __syncthreads();
  const int base8 = b * 8;
  const int bb = rbase[base8];
  // phase 1: count local nodes
#pragma unroll
  for (int r = 0; r < 8; ++r) {
    int s = rbase[base8 + r], e = rbase[base8 + r + 1];
    for (int i = s + t; i < e; i += 256) atomicAdd(&cnt64[recDS[i].x - v0], 1);
  }
  __syncthreads();
  // wave-0 scan of 64 counters; write rowptr
  if (t < 64) {
    int c = cnt64[t];
    int incl = c;
#pragma unroll
    for (int o = 1; o < 64; o <<= 1) {
      int g = __shfl_up(incl, o);
      if (t >= o) incl += g;
    }
    off64[t] = incl - c;
    if (t < nloc) rowptr[v0 + t + 1] = bb + incl;
  }
  __syncthreads();
  // phase 2: place + fused layer-1 exp
#pragma unroll
  for (int r = 0; r < 8; ++r) {
    int s = rbase[base8 + r], e = rbase[base8 + r + 1];
    for (int i = s + t; i < e; i += 256) {
      int2 q = recDS[i];
      float ae = recA[i];
      int loc = q.x - v0;
      int pos = bb + off64[loc] + atomicAdd(&fill64[loc], 1);
      float ex = __expf(LRELU(asrc[q.y] + adl[loc] + ae));
      edge[pos] = make_int2(q.y, __float_as_int(ex));
      atomicAdd(&rs[loc], ae);
    }
  }
  __syncthreads();
  if (t < nloc) asum[v0 + t] = rs[t];
}

// ---------------- layer-1 GEMM: x [n,5] @ W [5,64] (wave per node) -------------

__global__ void gemm1_k(const float* __restrict__ x, const float* __restrict__ W,
                        const float* __restrict__ as, const float* __restrict__ ad,
                        float* __restrict__ h, float* __restrict__ asrc,
                        float* __restrict__ adst, int n) {
  int lane = threadIdx.x & 63;
  int v = (blockIdx.x * blockDim.x + threadIdx.x) >> 6;
  if (v >= n) return;
  float acc = 0.f;
#pragma unroll
  for (int k = 0; k < 5; k++) acc += x[v * 5 + k] * W[k * 64 + lane];
  h[(size_t)v * 64 + lane] = acc;
  float ps = acc * as[lane], pd = acc * ad[lane];
#pragma unroll
  for (int off = 32; off > 0; off >>= 1) {
    ps += __shfl_down(ps, off);
    pd += __shfl_down(pd, off);
  }
  if (lane == 0) { asrc[v] = ps; adst[v] = pd; }
}

// ---------------- tiled GEMM: x [n,64] @ W [64,C], 4x4 register blocking -------

template <int C>
__global__ __launch_bounds__(256) void gemm_tile_k(
    const float* __restrict__ x, const float* __restrict__ W,
    const float* __restrict__ as, const float* __restrict__ ad,
    float* __restrict__ h, float* __restrict__ asrc, float* __restrict__ adst, int n) {
  constexpr int NT = 4096 / C;
  constexpr int CG = C / 4;
  constexpr int XTP = NT + 4;
  __shared__ float XT[64][XTP];
  __shared__ float Wl[64 * C];
  const int t = threadIdx.x;
  const int v0 = blockIdx.x * NT;
  for (int i = t; i < 64 * C; i += 256) Wl[i] = W[i];
  for (int i = t; i < NT * 64; i += 256) {
    int node = i >> 6, k = i & 63;
    int v = v0 + node;
    XT[k][node] = (v < n) ? x[(size_t)v * 64 + k] : 0.f;
  }
  __syncthreads();
  const int cg = t % CG, ng = t / CG;
  const int c0 = cg * 4, n0 = ng * 4;
  float acc[4][4] = {};
#pragma unroll 4
  for (int k = 0; k < 64; ++k) {
    const float4 xv = *(const float4*)&XT[k][n0];
    const float4 wv = *(const float4*)&Wl[k * C + c0];
    acc[0][0] += xv.x * wv.x; acc[0][1] += xv.x * wv.y; acc[0][2] += xv.x * wv.z; acc[0][3] += xv.x * wv.w;
    acc[1][0] += xv.y * wv.x; acc[1][1] += xv.y * wv.y; acc[1][2] += xv.y * wv.z; acc[1][3] += xv.y * wv.w;
    acc[2][0] += xv.z * wv.x; acc[2][1] += xv.z * wv.y; acc[2][2] += xv.z * wv.z; acc[2][3] += xv.z * wv.w;
    acc[3][0] += xv.w * wv.x; acc[3][1] += xv.w * wv.y; acc[3][2] += xv.w * wv.z; acc[3][3] += xv.w * wv.w;
  }
  float asv[4] = {as[c0], as[c0 + 1], as[c0 + 2], as[c0 + 3]};
  float adv[4] = {ad[c0], ad[c0 + 1], ad[c0 + 2], ad[c0 + 3]};
  float ps[4], pd[4];
#pragma unroll
  for (int ni = 0; ni < 4; ++ni) {
    ps[ni] = acc[ni][0] * asv[0] + acc[ni][1] * asv[1] + acc[ni][2] * asv[2] + acc[ni][3] * asv[3];
    pd[ni] = acc[ni][0] * adv[0] + acc[ni][1] * adv[1] + acc[ni][2] * adv[2] + acc[ni][3] * adv[3];
  }
#pragma unroll
  for (int off = CG / 2; off > 0; off >>= 1) {
#pragma unroll
    for (int ni = 0; ni < 4; ++ni) {
      ps[ni] += __shfl_xor(ps[ni], off);
      pd[ni] += __shfl_xor(pd[ni], off);
    }
  }
#pragma unroll
  for (int ni = 0; ni < 4; ++ni) {
    int v = v0 + n0 + ni;
    if (v < n) {
      float4 o = make_float4(acc[ni][0], acc[ni][1], acc[ni][2], acc[ni][3]);
      *(float4*)&h[(size_t)v * C + c0] = o;
      if (cg == 0) { asrc[v] = ps[ni]; adst[v] = pd[ni]; }
    }
  }
}

// ---------------- per-node softmax + aggregate ----------------
// edge[p] = (src, ex). LAYER=1: ex precomputed by bucket_build (read-only);
// raw attr sum in asum[]. LAYER>=2: ex field holds PREV layer's unnormalized
// ex; pass A replaces it in place. Deferred normalization via pinv/oinv.
template <int LAYER, int C>
__global__ __launch_bounds__(256) void agg_k(
    const int* __restrict__ rowptr, int2* __restrict__ edge,
    const float* __restrict__ h, const float* __restrict__ asrc,
    const float* __restrict__ adst, const float* __restrict__ asum,
    const float* __restrict__ pinv, const float* __restrict__ lp1,
    const float* __restrict__ lp2, float* __restrict__ oinv,
    float* __restrict__ ol1, float* __restrict__ ol2,
    const float* __restrict__ sw, const float* __restrict__ bias,
    float* __restrict__ out, int n) {
  constexpr int L = (C == 64) ? 64 : 32;
  const int lane = threadIdx.x & 63;
  const int ln = lane & (L - 1);
  const int wid = (blockIdx.x * blockDim.x + threadIdx.x) >> 6;
  const int v = (C == 64) ? wid : wid * 2 + (lane >> 5);
  if (v >= n) return;
  const float s = (LAYER == 1) ? 1.f : (LAYER == 2 ? sw[3] : sw[4]);
  const float fac = (LAYER == 1) ? 1.f : pinv[v];
  const float sf = s * fac;
  const int r0 = rowptr[v], r1 = rowptr[v + 1];
  const float av_d = adst[v], av_s = asrc[v];

  float rawsum = 0.f, den = 0.f;
  if (LAYER == 1) {
    for (int p = r0 + ln; p < r1; p += L) den += __int_as_float(edge[p].y);
  } else {
    for (int p = r0 + ln; p < r1; p += L) {
      int2 pk = edge[p];
      float a = __int_as_float(pk.y);
      rawsum += a;
      float lg = asrc[pk.x] + av_d + sf * a;
      float ex = __expf(LRELU(lg));
      edge[p].y = __float_as_int(ex);
      den += ex;
    }
    __threadfence_block();
  }
#pragma unroll
  for (int off = L / 2; off > 0; off >>= 1) {
    den += __shfl_xor(den, off);
    if (LAYER >= 2) rawsum += __shfl_xor(rawsum, off);
  }
  const float base = av_s + av_d;
  float la1 = 0.f, la2 = 0.f, e1 = 0.f, e2 = 0.f;
  if (LAYER >= 2) { la1 = fac * lp1[v]; e1 = __expf(LRELU(base + s * la1)); den += e1; }
  if (LAYER >= 3) { la2 = fac * lp2[v]; e2 = __expf(LRELU(base + s * la2)); den += e2; }
  int dd = (r1 - r0) + (LAYER - 1);
  if (dd < 1) dd = 1;
  float sum_a = (LAYER == 1) ? asum[v] : fac * rawsum + la1 + la2;
  float lmean = sum_a / (float)dd;
  float exm = __expf(LRELU(base + s * lmean));
  den += exm;
  float inv = 1.f / (den + 1e-16f);
  if (ln == 0) {
    if (LAYER < 3) oinv[v] = inv;
    if (LAYER == 1) ol1[v] = exm;
    if (LAYER == 2) { ol1[v] = e1; ol2[v] = exm; }
  }

  const int c = ln;
  const float* __restrict__ hc = h + c;
  float a0 = 0.f, a1 = 0.f, a2 = 0.f, a3 = 0.f;
  int p = r0;
  for (; p + 4 <= r1; p += 4) {
    int2 k0 = edge[p], k1 = edge[p + 1], k2 = edge[p + 2], k3 = edge[p + 3];
    a0 += __int_as_float(k0.y) * hc[(size_t)k0.x * C];
    a1 += __int_as_float(k1.y) * hc[(size_t)k1.x * C];
    a2 += __int_as_float(k2.y) * hc[(size_t)k2.x * C];
    a3 += __int_as_float(k3.y) * hc[(size_t)k3.x * C];
  }
  for (; p < r1; ++p) a0 += __int_as_float(edge[p].y) * hc[(size_t)edge[p].x * C];
  float hv = hc[(size_t)v * C];
  float acc = (a0 + a1) + (a2 + a3) + (e1 + e2 + exm) * hv;
  float o = acc * inv + bias[c];
  if (LAYER < 3) o = fmaxf(o, 0.f);
  out[(size_t)v * C + c] = o;
}

// ---------------- global mean pool (block per graph) ----------------

__global__ void pool_k(const float* __restrict__ h, const int* __restrict__ batch,
                       float* __restrict__ out, int n) {
  int g = blockIdx.x;
  int lo = 0, hi = n;
  while (lo < hi) { int m = (lo + hi) >> 1; if (batch[m] < g) lo = m + 1; else hi = m; }
  int start = lo;
  hi = n;
  while (lo < hi) { int m = (lo + hi) >> 1; if (batch[m] < g + 1) lo = m + 1; else hi = m; }
  int end = lo;
  int t = threadIdx.x;
  int c = t & 31, r = t >> 5;
  float acc = 0.f;
  for (int v = start + r; v < end; v += 8) acc += h[(size_t)v * 32 + c];
  __shared__ float s[256];
  s[t] = acc;
  __syncthreads();
  if (t < 128) s[t] += s[t + 128];
  __syncthreads();
  if (t < 64) s[t] += s[t + 64];
  __syncthreads();
  if (t < 32) {
    float tot = s[t] + s[t + 32];
    int cnt = end - start;
    out[g * 32 + t] = tot / (float)(cnt > 0 ? cnt : 1);
  }
}

// ---------------- launch ----------------

extern "C" void kernel_launch(void* const* d_in, const int* in_sizes, int n_in,
                              void* d_out, int out_size, void* d_ws, size_t ws_size,
                              hipStream_t stream) {
  const float* x     = (const float*)d_in[0];
  const int*   ei    = (const int*)d_in[1];
  const float* eattr = (const float*)d_in[2];
  const int*   batch = (const int*)d_in[3];
  const float *W1 = (const float*)d_in[4],  *as1 = (const float*)d_in[5],
              *ad1 = (const float*)d_in[6], *We1 = (const float*)d_in[7],
              *ae1 = (const float*)d_in[8], *b1  = (const float*)d_in[9];
  const float *W2 = (const float*)d_in[10], *as2 = (const float*)d_in[11],
              *ad2 = (const float*)d_in[12], *We2 = (const float*)d_in[13],
              *ae2 = (const float*)d_in[14], *b2  = (const float*)d_in[15];
  const float *W3 = (const float*)d_in[16], *as3 = (const float*)d_in[17],
              *ad3 = (const float*)d_in[18], *We3 = (const float*)d_in[19],
              *ae3 = (const float*)d_in[20], *b3  = (const float*)d_in[21];

  const int n = in_sizes[3];
  const int E = in_sizes[1] / 2;
  const int G = out_size / 32;
  const int* srcp = ei;
  const int* dstp = ei + E;
  const int B = (n + 63) >> BSH;   // buckets
  const int m = B * 8;             // bucket-replica counters

  char* w = (char*)d_ws;
  auto alloc = [&](size_t bytes) -> void* {
    void* p = (void*)w;
    w += (bytes + 255) & ~(size_t)255;
    return p;
  };
  int2*  recDS  = (int2*)alloc((size_t)E * 8);   // staging; aliased by O after S4
  float* recA   = (float*)alloc((size_t)E * 4);  // staging
  int2*  edge   = (int2*)alloc((size_t)E * 8);
  float* H      = (float*)alloc((size_t)n * 64 * 4);
  int*   cnt    = (int*)alloc((size_t)m * 4);
  int*   fillr  = (int*)alloc((size_t)m * 4);
  int*   rbase  = (int*)alloc((size_t)(m + 1) * 4);
  int*   rowptr = (int*)alloc((size_t)(n + 1) * 4);
  float* asum   = (float*)alloc((size_t)n * 4);
  float* asrcB  = (float*)alloc((size_t)n * 4);
  float* adstB  = (float*)alloc((size_t)n * 4);
  float* loopA  = (float*)alloc((size_t)n * 4);
  float* loopB1 = (float*)alloc((size_t)n * 4);
  float* loopB2 = (float*)alloc((size_t)n * 4);
  float* invA   = (float*)alloc((size_t)n * 4);
  float* invB   = (float*)alloc((size_t)n * 4);
  float* sw     = (float*)alloc(256);
  float* O      = (float*)recDS;  // alias: recDS dead after bucket_build_k

  dim3 blk256(256);
  dim3 gE((E + 255) / 256);
  dim3 gM((m + 255) / 256);
  dim3 gWave((n + 3) / 4);
  const int nw3 = (n + 1) / 2;
  dim3 gWave3((nw3 + 3) / 4);

  zero_cnt_k<<<gM, blk256, 0, stream>>>(cnt, fillr, m);
  small_weights_k<<<1, 64, 0, stream>>>(We1, ae1, We2, ae2, We3, ae3, sw);
  count_rep_k<<<gE, blk256, 0, stream>>>(dstp, cnt, E);
  scan_rep_k<<<1, 1024, 0, stream>>>(cnt, rbase, rowptr, m);
  append_rep_k<<<gE, blk256, 0, stream>>>(srcp, dstp, eattr, rbase, fillr, recDS, recA, sw, E);
  gemm1_k<<<gWave, blk256, 0, stream>>>(x, W1, as1, ad1, H, asrcB, adstB, n);
  bucket_build_k<<<B, blk256, 0, stream>>>(recDS, recA, rbase, asrcB, adstB,
                                           rowptr, asum, edge, n);
  // layer 1
  agg_k<1, 64><<<gWave, blk256, 0, stream>>>(rowptr, edge, H, asrcB, adstB, asum,
                                             nullptr, nullptr, nullptr,
                                             invA, loopA, nullptr, sw, b1, O, n);
  // layer 2
  gemm_tile_k<64><<<dim3((n + 63) / 64), blk256, 0, stream>>>(O, W2, as2, ad2, H, asrcB, adstB, n);
  agg_k<2, 64><<<gWave, blk256, 0, stream>>>(rowptr, edge, H, asrcB, adstB, nullptr,
                                             invA, loopA, nullptr,
                                             invB, loopB1, loopB2, sw, b2, O, n);
  // layer 3
  gemm_tile_k<32><<<dim3((n + 127) / 128), blk256, 0, stream>>>(O, W3, as3, ad3, H, asrcB, adstB, n);
  agg_k<3, 32><<<gWave3, blk256, 0, stream>>>(rowptr, edge, H, asrcB, adstB, nullptr,
                                              invB, loopB1, loopB2,
                                              nullptr, nullptr, nullptr, sw, b3, O, n);
  // pool
  pool_k<<<G, blk256, 0, stream>>>(O, batch, (float*)d_out, n);
}

// Round 5
// 705.917 us; speedup vs baseline: 1.3202x; 1.3178x over previous
//
#include <hip/hip_runtime.h>

#define LRELU(x) ((x) > 0.f ? (x) : 0.2f * (x))
#define SBSH 9      // 512 nodes per super-bucket
#define SBN 512
#define NB1 256     // blocks in count/append passes (each owns E/NB1 edges)
#define MAXSB 1024  // static LDS cap on super-bucket count

// ---------------- small weights ----------------
// sw[0..2] = We1^T @ ae1 per edge-dim row; sw[3] = We2 . ae2; sw[4] = We3 . ae3
__global__ void small_weights_k(const float* __restrict__ We1, const float* __restrict__ ae1,
                                const float* __restrict__ We2, const float* __restrict__ ae2,
                                const float* __restrict__ We3, const float* __restrict__ ae3,
                                float* __restrict__ sw) {
  int t = threadIdx.x;  // 64 threads = 1 wave
  float v0 = We1[t] * ae1[t];
  float v1 = We1[64 + t] * ae1[t];
  float v2 = We1[128 + t] * ae1[t];
  float v3 = We2[t] * ae2[t];
  float v4 = (t < 32) ? We3[t] * ae3[t] : 0.f;
#pragma unroll
  for (int off = 32; off > 0; off >>= 1) {
    v0 += __shfl_down(v0, off);
    v1 += __shfl_down(v1, off);
    v2 += __shfl_down(v2, off);
    v3 += __shfl_down(v3, off);
    v4 += __shfl_down(v4, off);
  }
  if (t == 0) { sw[0] = v0; sw[1] = v1; sw[2] = v2; sw[3] = v3; sw[4] = v4; }
}

// ---------------- CSR build, atomic-free staging ----------------
// S1: per-(super-bucket, block) exact counts. Chunk per block fixed.
__global__ __launch_bounds__(256) void count1_k(const int* __restrict__ dst,
                                                int* __restrict__ gcnt, int E, int NSB) {
  __shared__ int cnt[MAXSB];
  const int t = threadIdx.x, blk = blockIdx.x;
  for (int i = t; i < NSB; i += 256) cnt[i] = 0;
  __syncthreads();
  const int CE = (E + NB1 - 1) / NB1;
  const int e0 = blk * CE, e1 = min(E, e0 + CE);
  for (int e = e0 + t; e < e1; e += 256) {
    int d = __builtin_nontemporal_load(&dst[e]);
    atomicAdd(&cnt[d >> SBSH], 1);
  }
  __syncthreads();
  for (int i = t; i < NSB; i += 256) gcnt[i * NB1 + blk] = cnt[i];  // sb-major
}

// S2: exclusive scan over M = NSB*NB1 counters (one block); gbase[M] = E
__global__ __launch_bounds__(1024) void scan_gbase_k(const int* __restrict__ gcnt,
                                                     int* __restrict__ gbase,
                                                     int* __restrict__ rowptr, int M) {
  __shared__ int part[1024];
  const int t = threadIdx.x;
  const int per = (M + 1023) / 1024;
  const int s0 = min(M, t * per), e0 = min(M, s0 + per);
  int sum = 0;
  for (int i = s0; i < e0; ++i) sum += gcnt[i];
  part[t] = sum;
  __syncthreads();
  for (int off = 1; off < 1024; off <<= 1) {
    int add = (t >= off) ? part[t - off] : 0;
    __syncthreads();
    part[t] += add;
    __syncthreads();
  }
  int excl = (t == 0) ? 0 : part[t - 1];
  for (int i = s0; i < e0; ++i) { gbase[i] = excl; excl += gcnt[i]; }
  if (t == 1023) gbase[M] = part[1023];
  if (t == 0) rowptr[0] = 0;
}

// S3: append into block-private reservations (LDS cursors, NO global atomics)
__global__ __launch_bounds__(256) void append2_k(
    const int* __restrict__ src, const int* __restrict__ dst,
    const float* __restrict__ eattr, const int* __restrict__ gbase,
    int2* __restrict__ recDS, float* __restrict__ recA,
    const float* __restrict__ sw, int E, int NSB) {
  __shared__ int base[MAXSB];
  __shared__ int off[MAXSB];
  const int t = threadIdx.x, blk = blockIdx.x;
  for (int i = t; i < NSB; i += 256) { base[i] = gbase[i * NB1 + blk]; off[i] = 0; }
  __syncthreads();
  const float w0 = sw[0], w1 = sw[1], w2 = sw[2];
  const int CE = (E + NB1 - 1) / NB1;
  const int e0 = blk * CE, e1 = min(E, e0 + CE);
  for (int e = e0 + t; e < e1; e += 256) {
    int d = __builtin_nontemporal_load(&dst[e]);
    int sv = __builtin_nontemporal_load(&src[e]);
    float a0 = __builtin_nontemporal_load(&eattr[e * 3]);
    float a1 = __builtin_nontemporal_load(&eattr[e * 3 + 1]);
    float a2 = __builtin_nontemporal_load(&eattr[e * 3 + 2]);
    float ae = a0 * w0 + a1 * w1 + a2 * w2;
    int sb = d >> SBSH;
    int pos = base[sb] + atomicAdd(&off[sb], 1);  // LDS atomic
    recDS[pos] = make_int2(d, sv);
    recA[pos] = ae;
  }
}

// S4: one block per super-bucket: count 512 nodes, block-scan -> rowptr,
// place final edge[] = (src, layer-1 ex) into L2-local window; asum in LDS.
__global__ __launch_bounds__(1024) void sb_build_k(
    const int2* __restrict__ recDS, const float* __restrict__ recA,
    const int* __restrict__ gbase, const float* __restrict__ asrc,
    const float* __restrict__ adst, int* __restrict__ rowptr,
    float* __restrict__ asum, int2* __restrict__ edge, int n, int NSB) {
  __shared__ int cnt[SBN];
  __shared__ int sc[SBN];
  __shared__ int fill[SBN];
  __shared__ float adl[SBN];
  __shared__ float rs[SBN];
  const int t = threadIdx.x, sb = blockIdx.x;
  const int v0 = sb << SBSH;
  const int nloc = min(SBN, n - v0);
  if (t < SBN) {
    cnt[t] = 0; fill[t] = 0; rs[t] = 0.f;
    adl[t] = (t < nloc) ? adst[v0 + t] : 0.f;
  }
  __syncthreads();
  const int seg0 = gbase[sb * NB1], seg1 = gbase[(sb + 1) * NB1];
  // pass 1: count
  for (int i = seg0 + t; i < seg1; i += 1024) atomicAdd(&cnt[recDS[i].x - v0], 1);
  __syncthreads();
  if (t < SBN) sc[t] = cnt[t];
  __syncthreads();
  // inclusive scan over 512 (all threads hit barriers)
  for (int off = 1; off < SBN; off <<= 1) {
    int add = (t < SBN && t >= off) ? sc[t - off] : 0;
    __syncthreads();
    if (t < SBN) sc[t] += add;
    __syncthreads();
  }
  if (t < nloc) rowptr[v0 + t + 1] = seg0 + sc[t];
  // pass 2: place + fused layer-1 exp + raw-attr sums
  for (int i = seg0 + t; i < seg1; i += 1024) {
    int2 q = recDS[i];
    float ae = recA[i];
    int loc = q.x - v0;
    int pos = seg0 + (sc[loc] - cnt[loc]) + atomicAdd(&fill[loc], 1);
    float ex = __expf(LRELU(asrc[q.y] + adl[loc] + ae));
    edge[pos] = make_int2(q.y, __float_as_int(ex));
    atomicAdd(&rs[loc], ae);
  }
  __syncthreads();
  if (t < nloc) asum[v0 + t] = rs[t];
}

// ---------------- layer-1 GEMM: x [n,5] @ W [5,64] (wave per node) -------------

__global__ void gemm1_k(const float* __restrict__ x, const float* __restrict__ W,
                        const float* __restrict__ as, const float* __restrict__ ad,
                        float* __restrict__ h, float* __restrict__ asrc,
                        float* __restrict__ adst, int n) {
  int lane = threadIdx.x & 63;
  int v = (blockIdx.x * blockDim.x + threadIdx.x) >> 6;
  if (v >= n) return;
  float acc = 0.f;
#pragma unroll
  for (int k = 0; k < 5; k++) acc += x[v * 5 + k] * W[k * 64 + lane];
  h[(size_t)v * 64 + lane] = acc;
  float ps = acc * as[lane], pd = acc * ad[lane];
#pragma unroll
  for (int off = 32; off > 0; off >>= 1) {
    ps += __shfl_down(ps, off);
    pd += __shfl_down(pd, off);
  }
  if (lane == 0) { asrc[v] = ps; adst[v] = pd; }
}

// ---------------- tiled GEMM: x [n,64] @ W [64,C], 4x4 register blocking -------

template <int C>
__global__ __launch_bounds__(256) void gemm_tile_k(
    const float* __restrict__ x, const float* __restrict__ W,
    const float* __restrict__ as, const float* __restrict__ ad,
    float* __restrict__ h, float* __restrict__ asrc, float* __restrict__ adst, int n) {
  constexpr int NT = 4096 / C;
  constexpr int CG = C / 4;
  constexpr int XTP = NT + 4;
  __shared__ float XT[64][XTP];
  __shared__ float Wl[64 * C];
  const int t = threadIdx.x;
  const int v0 = blockIdx.x * NT;
  for (int i = t; i < 64 * C; i += 256) Wl[i] = W[i];
  for (int i = t; i < NT * 64; i += 256) {
    int node = i >> 6, k = i & 63;
    int v = v0 + node;
    XT[k][node] = (v < n) ? x[(size_t)v * 64 + k] : 0.f;
  }
  __syncthreads();
  const int cg = t % CG, ng = t / CG;
  const int c0 = cg * 4, n0 = ng * 4;
  float acc[4][4] = {};
#pragma unroll 4
  for (int k = 0; k < 64; ++k) {
    const float4 xv = *(const float4*)&XT[k][n0];
    const float4 wv = *(const float4*)&Wl[k * C + c0];
    acc[0][0] += xv.x * wv.x; acc[0][1] += xv.x * wv.y; acc[0][2] += xv.x * wv.z; acc[0][3] += xv.x * wv.w;
    acc[1][0] += xv.y * wv.x; acc[1][1] += xv.y * wv.y; acc[1][2] += xv.y * wv.z; acc[1][3] += xv.y * wv.w;
    acc[2][0] += xv.z * wv.x; acc[2][1] += xv.z * wv.y; acc[2][2] += xv.z * wv.z; acc[2][3] += xv.z * wv.w;
    acc[3][0] += xv.w * wv.x; acc[3][1] += xv.w * wv.y; acc[3][2] += xv.w * wv.z; acc[3][3] += xv.w * wv.w;
  }
  float asv[4] = {as[c0], as[c0 + 1], as[c0 + 2], as[c0 + 3]};
  float adv[4] = {ad[c0], ad[c0 + 1], ad[c0 + 2], ad[c0 + 3]};
  float ps[4], pd[4];
#pragma unroll
  for (int ni = 0; ni < 4; ++ni) {
    ps[ni] = acc[ni][0] * asv[0] + acc[ni][1] * asv[1] + acc[ni][2] * asv[2] + acc[ni][3] * asv[3];
    pd[ni] = acc[ni][0] * adv[0] + acc[ni][1] * adv[1] + acc[ni][2] * adv[2] + acc[ni][3] * adv[3];
  }
#pragma unroll
  for (int off = CG / 2; off > 0; off >>= 1) {
#pragma unroll
    for (int ni = 0; ni < 4; ++ni) {
      ps[ni] += __shfl_xor(ps[ni], off);
      pd[ni] += __shfl_xor(pd[ni], off);
    }
  }
#pragma unroll
  for (int ni = 0; ni < 4; ++ni) {
    int v = v0 + n0 + ni;
    if (v < n) {
      float4 o = make_float4(acc[ni][0], acc[ni][1], acc[ni][2], acc[ni][3]);
      *(float4*)&h[(size_t)v * C + c0] = o;
      if (cg == 0) { asrc[v] = ps[ni]; adst[v] = pd[ni]; }
    }
  }
}

// ---------------- per-node softmax + aggregate ----------------
// edge[p] = (src, ex). LAYER=1: ex precomputed by sb_build (read-only);
// raw attr sum in asum[]. LAYER>=2: ex field holds PREV layer's unnormalized
// ex; pass A replaces it in place. Deferred normalization via pinv/oinv.
template <int LAYER, int C>
__global__ __launch_bounds__(256) void agg_k(
    const int* __restrict__ rowptr, int2* __restrict__ edge,
    const float* __restrict__ h, const float* __restrict__ asrc,
    const float* __restrict__ adst, const float* __restrict__ asum,
    const float* __restrict__ pinv, const float* __restrict__ lp1,
    const float* __restrict__ lp2, float* __restrict__ oinv,
    float* __restrict__ ol1, float* __restrict__ ol2,
    const float* __restrict__ sw, const float* __restrict__ bias,
    float* __restrict__ out, int n) {
  constexpr int L = (C == 64) ? 64 : 32;
  const int lane = threadIdx.x & 63;
  const int ln = lane & (L - 1);
  const int wid = (blockIdx.x * blockDim.x + threadIdx.x) >> 6;
  const int v = (C == 64) ? wid : wid * 2 + (lane >> 5);
  if (v >= n) return;
  const float s = (LAYER == 1) ? 1.f : (LAYER == 2 ? sw[3] : sw[4]);
  const float fac = (LAYER == 1) ? 1.f : pinv[v];
  const float sf = s * fac;
  const int r0 = rowptr[v], r1 = rowptr[v + 1];
  const float av_d = adst[v], av_s = asrc[v];

  float rawsum = 0.f, den = 0.f;
  if (LAYER == 1) {
    for (int p = r0 + ln; p < r1; p += L) den += __int_as_float(edge[p].y);
  } else {
    for (int p = r0 + ln; p < r1; p += L) {
      int2 pk = edge[p];
      float a = __int_as_float(pk.y);
      rawsum += a;
      float lg = asrc[pk.x] + av_d + sf * a;
      float ex = __expf(LRELU(lg));
      edge[p].y = __float_as_int(ex);
      den += ex;
    }
    __threadfence_block();
  }
#pragma unroll
  for (int off = L / 2; off > 0; off >>= 1) {
    den += __shfl_xor(den, off);
    if (LAYER >= 2) rawsum += __shfl_xor(rawsum, off);
  }
  const float base = av_s + av_d;
  float la1 = 0.f, la2 = 0.f, e1 = 0.f, e2 = 0.f;
  if (LAYER >= 2) { la1 = fac * lp1[v]; e1 = __expf(LRELU(base + s * la1)); den += e1; }
  if (LAYER >= 3) { la2 = fac * lp2[v]; e2 = __expf(LRELU(base + s * la2)); den += e2; }
  int dd = (r1 - r0) + (LAYER - 1);
  if (dd < 1) dd = 1;
  float sum_a = (LAYER == 1) ? asum[v] : fac * rawsum + la1 + la2;
  float lmean = sum_a / (float)dd;
  float exm = __expf(LRELU(base + s * lmean));
  den += exm;
  float inv = 1.f / (den + 1e-16f);
  if (ln == 0) {
    if (LAYER < 3) oinv[v] = inv;
    if (LAYER == 1) ol1[v] = exm;
    if (LAYER == 2) { ol1[v] = e1; ol2[v] = exm; }
  }

  const int c = ln;
  const float* __restrict__ hc = h + c;
  float a0 = 0.f, a1 = 0.f, a2 = 0.f, a3 = 0.f;
  int p = r0;
  for (; p + 4 <= r1; p += 4) {
    int2 k0 = edge[p], k1 = edge[p + 1], k2 = edge[p + 2], k3 = edge[p + 3];
    a0 += __int_as_float(k0.y) * hc[(size_t)k0.x * C];
    a1 += __int_as_float(k1.y) * hc[(size_t)k1.x * C];
    a2 += __int_as_float(k2.y) * hc[(size_t)k2.x * C];
    a3 += __int_as_float(k3.y) * hc[(size_t)k3.x * C];
  }
  for (; p < r1; ++p) a0 += __int_as_float(edge[p].y) * hc[(size_t)edge[p].x * C];
  float hv = hc[(size_t)v * C];
  float acc = (a0 + a1) + (a2 + a3) + (e1 + e2 + exm) * hv;
  float o = acc * inv + bias[c];
  if (LAYER < 3) o = fmaxf(o, 0.f);
  out[(size_t)v * C + c] = o;
}

// ---------------- global mean pool (block per graph) ----------------

__global__ void pool_k(const float* __restrict__ h, const int* __restrict__ batch,
                       float* __restrict__ out, int n) {
  int g = blockIdx.x;
  int lo = 0, hi = n;
  while (lo < hi) { int m = (lo + hi) >> 1; if (batch[m] < g) lo = m + 1; else hi = m; }
  int start = lo;
  hi = n;
  while (lo < hi) { int m = (lo + hi) >> 1; if (batch[m] < g + 1) lo = m + 1; else hi = m; }
  int end = lo;
  int t = threadIdx.x;
  int c = t & 31, r = t >> 5;
  float acc = 0.f;
  for (int v = start + r; v < end; v += 8) acc += h[(size_t)v * 32 + c];
  __shared__ float s[256];
  s[t] = acc;
  __syncthreads();
  if (t < 128) s[t] += s[t + 128];
  __syncthreads();
  if (t < 64) s[t] += s[t + 64];
  __syncthreads();
  if (t < 32) {
    float tot = s[t] + s[t + 32];
    int cnt = end - start;
    out[g * 32 + t] = tot / (float)(cnt > 0 ? cnt : 1);
  }
}

// ---------------- launch ----------------

extern "C" void kernel_launch(void* const* d_in, const int* in_sizes, int n_in,
                              void* d_out, int out_size, void* d_ws, size_t ws_size,
                              hipStream_t stream) {
  const float* x     = (const float*)d_in[0];
  const int*   ei    = (const int*)d_in[1];
  const float* eattr = (const float*)d_in[2];
  const int*   batch = (const int*)d_in[3];
  const float *W1 = (const float*)d_in[4],  *as1 = (const float*)d_in[5],
              *ad1 = (const float*)d_in[6], *We1 = (const float*)d_in[7],
              *ae1 = (const float*)d_in[8], *b1  = (const float*)d_in[9];
  const float *W2 = (const float*)d_in[10], *as2 = (const float*)d_in[11],
              *ad2 = (const float*)d_in[12], *We2 = (const float*)d_in[13],
              *ae2 = (const float*)d_in[14], *b2  = (const float*)d_in[15];
  const float *W3 = (const float*)d_in[16], *as3 = (const float*)d_in[17],
              *ad3 = (const float*)d_in[18], *We3 = (const float*)d_in[19],
              *ae3 = (const float*)d_in[20], *b3  = (const float*)d_in[21];

  const int n = in_sizes[3];
  const int E = in_sizes[1] / 2;
  const int G = out_size / 32;
  const int* srcp = ei;
  const int* dstp = ei + E;
  const int NSB = (n + SBN - 1) >> SBSH;  // super-buckets
  const int M = NSB * NB1;                // count-matrix entries

  char* w = (char*)d_ws;
  auto alloc = [&](size_t bytes) -> void* {
    void* p = (void*)w;
    w += (bytes + 255) & ~(size_t)255;
    return p;
  };
  int2*  recDS  = (int2*)alloc((size_t)E * 8);   // staging; aliased by O after sb_build
  float* recA   = (float*)alloc((size_t)E * 4);  // staging
  int2*  edge   = (int2*)alloc((size_t)E * 8);
  float* H      = (float*)alloc((size_t)n * 64 * 4);
  int*   gcnt   = (int*)alloc((size_t)M * 4);
  int*   gbase  = (int*)alloc((size_t)(M + 1) * 4);
  int*   rowptr = (int*)alloc((size_t)(n + 1) * 4);
  float* asum   = (float*)alloc((size_t)n * 4);
  float* asrcB  = (float*)alloc((size_t)n * 4);
  float* adstB  = (float*)alloc((size_t)n * 4);
  float* loopA  = (float*)alloc((size_t)n * 4);
  float* loopB1 = (float*)alloc((size_t)n * 4);
  float* loopB2 = (float*)alloc((size_t)n * 4);
  float* invA   = (float*)alloc((size_t)n * 4);
  float* invB   = (float*)alloc((size_t)n * 4);
  float* sw     = (float*)alloc(256);
  float* O      = (float*)recDS;  // alias: recDS dead after sb_build_k

  dim3 blk256(256);
  dim3 gWave((n + 3) / 4);
  const int nw3 = (n + 1) / 2;
  dim3 gWave3((nw3 + 3) / 4);

  small_weights_k<<<1, 64, 0, stream>>>(We1, ae1, We2, ae2, We3, ae3, sw);
  count1_k<<<NB1, blk256, 0, stream>>>(dstp, gcnt, E, NSB);
  scan_gbase_k<<<1, 1024, 0, stream>>>(gcnt, gbase, rowptr, M);
  append2_k<<<NB1, blk256, 0, stream>>>(srcp, dstp, eattr, gbase, recDS, recA, sw, E, NSB);
  gemm1_k<<<gWave, blk256, 0, stream>>>(x, W1, as1, ad1, H, asrcB, adstB, n);
  sb_build_k<<<NSB, 1024, 0, stream>>>(recDS, recA, gbase, asrcB, adstB,
                                       rowptr, asum, edge, n, NSB);
  // layer 1
  agg_k<1, 64><<<gWave, blk256, 0, stream>>>(rowptr, edge, H, asrcB, adstB, asum,
                                             nullptr, nullptr, nullptr,
                                             invA, loopA, nullptr, sw, b1, O, n);
  // layer 2
  gemm_tile_k<64><<<dim3((n + 63) / 64), blk256, 0, stream>>>(O, W2, as2, ad2, H, asrcB, adstB, n);
  agg_k<2, 64><<<gWave, blk256, 0, stream>>>(rowptr, edge, H, asrcB, adstB, nullptr,
                                             invA, loopA, nullptr,
                                             invB, loopB1, loopB2, sw, b2, O, n);
  // layer 3
  gemm_tile_k<32><<<dim3((n + 127) / 128), blk256, 0, stream>>>(O, W3, as3, ad3, H, asrcB, adstB, n);
  agg_k<3, 32><<<gWave3, blk256, 0, stream>>>(rowptr, edge, H, asrcB, adstB, nullptr,
                                              invB, loopB1, loopB2,
                                              nullptr, nullptr, nullptr, sw, b3, O, n);
  // pool
  pool_k<<<G, blk256, 0, stream>>>(O, batch, (float*)d_out, n);
}

// Round 6
// 651.863 us; speedup vs baseline: 1.4297x; 1.0829x over previous
//
#include <hip/hip_runtime.h>
#include <hip/hip_fp16.h>

#define LRELU(x) ((x) > 0.f ? (x) : 0.2f * (x))
#define SBSH 9      // 512 nodes per super-bucket
#define SBN 512
#define NB1 256     // blocks in count/append passes (each owns E/NB1 edges)
#define MAXSB 1024  // static LDS cap on super-bucket count

// ---------------- small weights ----------------
// sw[0..2] = We1^T @ ae1 per edge-dim row; sw[3] = We2 . ae2; sw[4] = We3 . ae3
__global__ void small_weights_k(const float* __restrict__ We1, const float* __restrict__ ae1,
                                const float* __restrict__ We2, const float* __restrict__ ae2,
                                const float* __restrict__ We3, const float* __restrict__ ae3,
                                float* __restrict__ sw) {
  int t = threadIdx.x;  // 64 threads = 1 wave
  float v0 = We1[t] * ae1[t];
  float v1 = We1[64 + t] * ae1[t];
  float v2 = We1[128 + t] * ae1[t];
  float v3 = We2[t] * ae2[t];
  float v4 = (t < 32) ? We3[t] * ae3[t] : 0.f;
#pragma unroll
  for (int off = 32; off > 0; off >>= 1) {
    v0 += __shfl_down(v0, off);
    v1 += __shfl_down(v1, off);
    v2 += __shfl_down(v2, off);
    v3 += __shfl_down(v3, off);
    v4 += __shfl_down(v4, off);
  }
  if (t == 0) { sw[0] = v0; sw[1] = v1; sw[2] = v2; sw[3] = v3; sw[4] = v4; }
}

// ---------------- CSR build, atomic-free staging ----------------
// S1: per-(super-bucket, block) exact counts. Chunk per block fixed.
__global__ __launch_bounds__(256) void count1_k(const int* __restrict__ dst,
                                                int* __restrict__ gcnt, int E, int NSB) {
  __shared__ int cnt[MAXSB];
  const int t = threadIdx.x, blk = blockIdx.x;
  for (int i = t; i < NSB; i += 256) cnt[i] = 0;
  __syncthreads();
  const int CE = (E + NB1 - 1) / NB1;
  const int e0 = blk * CE, e1 = min(E, e0 + CE);
  for (int e = e0 + t; e < e1; e += 256) {
    int d = __builtin_nontemporal_load(&dst[e]);
    atomicAdd(&cnt[d >> SBSH], 1);
  }
  __syncthreads();
  for (int i = t; i < NSB; i += 256) gcnt[i * NB1 + blk] = cnt[i];  // sb-major
}

// S2: exclusive scan over M = NSB*NB1 counters (one block); gbase[M] = E
__global__ __launch_bounds__(1024) void scan_gbase_k(const int* __restrict__ gcnt,
                                                     int* __restrict__ gbase,
                                                     int* __restrict__ rowptr, int M) {
  __shared__ int part[1024];
  const int t = threadIdx.x;
  const int per = (M + 1023) / 1024;
  const int s0 = min(M, t * per), e0 = min(M, s0 + per);
  int sum = 0;
  for (int i = s0; i < e0; ++i) sum += gcnt[i];
  part[t] = sum;
  __syncthreads();
  for (int off = 1; off < 1024; off <<= 1) {
    int add = (t >= off) ? part[t - off] : 0;
    __syncthreads();
    part[t] += add;
    __syncthreads();
  }
  int excl = (t == 0) ? 0 : part[t - 1];
  for (int i = s0; i < e0; ++i) { gbase[i] = excl; excl += gcnt[i]; }
  if (t == 1023) gbase[M] = part[1023];
  if (t == 0) rowptr[0] = 0;
}

// S3: append into block-private reservations (LDS cursors, NO global atomics)
__global__ __launch_bounds__(256) void append2_k(
    const int* __restrict__ src, const int* __restrict__ dst,
    const float* __restrict__ eattr, const int* __restrict__ gbase,
    int2* __restrict__ recDS, float* __restrict__ recA,
    const float* __restrict__ sw, int E, int NSB) {
  __shared__ int base[MAXSB];
  __shared__ int off[MAXSB];
  const int t = threadIdx.x, blk = blockIdx.x;
  for (int i = t; i < NSB; i += 256) { base[i] = gbase[i * NB1 + blk]; off[i] = 0; }
  __syncthreads();
  const float w0 = sw[0], w1 = sw[1], w2 = sw[2];
  const int CE = (E + NB1 - 1) / NB1;
  const int e0 = blk * CE, e1 = min(E, e0 + CE);
  for (int e = e0 + t; e < e1; e += 256) {
    int d = __builtin_nontemporal_load(&dst[e]);
    int sv = __builtin_nontemporal_load(&src[e]);
    float a0 = __builtin_nontemporal_load(&eattr[e * 3]);
    float a1 = __builtin_nontemporal_load(&eattr[e * 3 + 1]);
    float a2 = __builtin_nontemporal_load(&eattr[e * 3 + 2]);
    float ae = a0 * w0 + a1 * w1 + a2 * w2;
    int sb = d >> SBSH;
    int pos = base[sb] + atomicAdd(&off[sb], 1);  // LDS atomic
    recDS[pos] = make_int2(d, sv);
    recA[pos] = ae;
  }
}

// S4: one block per super-bucket: count 512 nodes, block-scan -> rowptr,
// place final edge[] = (src, layer-1 ex) into L2-local window; asum in LDS.
__global__ __launch_bounds__(1024) void sb_build_k(
    const int2* __restrict__ recDS, const float* __restrict__ recA,
    const int* __restrict__ gbase, const float* __restrict__ asrc,
    const float* __restrict__ adst, int* __restrict__ rowptr,
    float* __restrict__ asum, int2* __restrict__ edge, int n, int NSB) {
  __shared__ int cnt[SBN];
  __shared__ int sc[SBN];
  __shared__ int fill[SBN];
  __shared__ float adl[SBN];
  __shared__ float rs[SBN];
  const int t = threadIdx.x, sb = blockIdx.x;
  const int v0 = sb << SBSH;
  const int nloc = min(SBN, n - v0);
  if (t < SBN) {
    cnt[t] = 0; fill[t] = 0; rs[t] = 0.f;
    adl[t] = (t < nloc) ? adst[v0 + t] : 0.f;
  }
  __syncthreads();
  const int seg0 = gbase[sb * NB1], seg1 = gbase[(sb + 1) * NB1];
  // pass 1: count
  for (int i = seg0 + t; i < seg1; i += 1024) atomicAdd(&cnt[recDS[i].x - v0], 1);
  __syncthreads();
  if (t < SBN) sc[t] = cnt[t];
  __syncthreads();
  // inclusive scan over 512 (all threads hit barriers)
  for (int off = 1; off < SBN; off <<= 1) {
    int add = (t < SBN && t >= off) ? sc[t - off] : 0;
    __syncthreads();
    if (t < SBN) sc[t] += add;
    __syncthreads();
  }
  if (t < nloc) rowptr[v0 + t + 1] = seg0 + sc[t];
  // pass 2: place + fused layer-1 exp + raw-attr sums
  for (int i = seg0 + t; i < seg1; i += 1024) {
    int2 q = recDS[i];
    float ae = recA[i];
    int loc = q.x - v0;
    int pos = seg0 + (sc[loc] - cnt[loc]) + atomicAdd(&fill[loc], 1);
    float ex = __expf(LRELU(asrc[q.y] + adl[loc] + ae));
    edge[pos] = make_int2(q.y, __float_as_int(ex));
    atomicAdd(&rs[loc], ae);
  }
  __syncthreads();
  if (t < nloc) asum[v0 + t] = rs[t];
}

// ---------------- layer-1 GEMM: x [n,5] @ W [5,64] (wave per node) -------------
// h stored fp16 (gather payload); asrc/adst from fp32 accumulators.

__global__ void gemm1_k(const float* __restrict__ x, const float* __restrict__ W,
                        const float* __restrict__ as, const float* __restrict__ ad,
                        __half* __restrict__ h, float* __restrict__ asrc,
                        float* __restrict__ adst, int n) {
  int lane = threadIdx.x & 63;
  int v = (blockIdx.x * blockDim.x + threadIdx.x) >> 6;
  if (v >= n) return;
  float acc = 0.f;
#pragma unroll
  for (int k = 0; k < 5; k++) acc += x[v * 5 + k] * W[k * 64 + lane];
  h[(size_t)v * 64 + lane] = __float2half(acc);
  float ps = acc * as[lane], pd = acc * ad[lane];
#pragma unroll
  for (int off = 32; off > 0; off >>= 1) {
    ps += __shfl_down(ps, off);
    pd += __shfl_down(pd, off);
  }
  if (lane == 0) { asrc[v] = ps; adst[v] = pd; }
}

// ---------------- tiled GEMM: x [n,64] @ W [64,C], 4x4 register blocking -------

template <int C>
__global__ __launch_bounds__(256) void gemm_tile_k(
    const float* __restrict__ x, const float* __restrict__ W,
    const float* __restrict__ as, const float* __restrict__ ad,
    __half* __restrict__ h, float* __restrict__ asrc, float* __restrict__ adst, int n) {
  constexpr int NT = 4096 / C;
  constexpr int CG = C / 4;
  constexpr int XTP = NT + 4;
  __shared__ float XT[64][XTP];
  __shared__ float Wl[64 * C];
  const int t = threadIdx.x;
  const int v0 = blockIdx.x * NT;
  for (int i = t; i < 64 * C; i += 256) Wl[i] = W[i];
  for (int i = t; i < NT * 64; i += 256) {
    int node = i >> 6, k = i & 63;
    int v = v0 + node;
    XT[k][node] = (v < n) ? x[(size_t)v * 64 + k] : 0.f;
  }
  __syncthreads();
  const int cg = t % CG, ng = t / CG;
  const int c0 = cg * 4, n0 = ng * 4;
  float acc[4][4] = {};
#pragma unroll 4
  for (int k = 0; k < 64; ++k) {
    const float4 xv = *(const float4*)&XT[k][n0];
    const float4 wv = *(const float4*)&Wl[k * C + c0];
    acc[0][0] += xv.x * wv.x; acc[0][1] += xv.x * wv.y; acc[0][2] += xv.x * wv.z; acc[0][3] += xv.x * wv.w;
    acc[1][0] += xv.y * wv.x; acc[1][1] += xv.y * wv.y; acc[1][2] += xv.y * wv.z; acc[1][3] += xv.y * wv.w;
    acc[2][0] += xv.z * wv.x; acc[2][1] += xv.z * wv.y; acc[2][2] += xv.z * wv.z; acc[2][3] += xv.z * wv.w;
    acc[3][0] += xv.w * wv.x; acc[3][1] += xv.w * wv.y; acc[3][2] += xv.w * wv.z; acc[3][3] += xv.w * wv.w;
  }
  float asv[4] = {as[c0], as[c0 + 1], as[c0 + 2], as[c0 + 3]};
  float adv[4] = {ad[c0], ad[c0 + 1], ad[c0 + 2], ad[c0 + 3]};
  float ps[4], pd[4];
#pragma unroll
  for (int ni = 0; ni < 4; ++ni) {
    ps[ni] = acc[ni][0] * asv[0] + acc[ni][1] * asv[1] + acc[ni][2] * asv[2] + acc[ni][3] * asv[3];
    pd[ni] = acc[ni][0] * adv[0] + acc[ni][1] * adv[1] + acc[ni][2] * adv[2] + acc[ni][3] * adv[3];
  }
#pragma unroll
  for (int off = CG / 2; off > 0; off >>= 1) {
#pragma unroll
    for (int ni = 0; ni < 4; ++ni) {
      ps[ni] += __shfl_xor(ps[ni], off);
      pd[ni] += __shfl_xor(pd[ni], off);
    }
  }
#pragma unroll
  for (int ni = 0; ni < 4; ++ni) {
    int v = v0 + n0 + ni;
    if (v < n) {
      union { __half hh[4]; uint2 u; } pk;
      pk.hh[0] = __float2half(acc[ni][0]);
      pk.hh[1] = __float2half(acc[ni][1]);
      pk.hh[2] = __float2half(acc[ni][2]);
      pk.hh[3] = __float2half(acc[ni][3]);
      *(uint2*)&h[(size_t)v * C + c0] = pk.u;
      if (cg == 0) { asrc[v] = ps[ni]; adst[v] = pd[ni]; }
    }
  }
}

// ---------------- per-node softmax + aggregate ----------------
// edge[p] = (src, ex). LAYER=1: ex precomputed by sb_build (read-only);
// raw attr sum in asum[]. LAYER>=2: ex field holds PREV layer's unnormalized
// ex; pass A replaces it in place. Deferred normalization via pinv/oinv.
// h is fp16 (gather payload); out stays fp32.
template <int LAYER, int C>
__global__ __launch_bounds__(256) void agg_k(
    const int* __restrict__ rowptr, int2* __restrict__ edge,
    const __half* __restrict__ h, const float* __restrict__ asrc,
    const float* __restrict__ adst, const float* __restrict__ asum,
    const float* __restrict__ pinv, const float* __restrict__ lp1,
    const float* __restrict__ lp2, float* __restrict__ oinv,
    float* __restrict__ ol1, float* __restrict__ ol2,
    const float* __restrict__ sw, const float* __restrict__ bias,
    float* __restrict__ out, int n) {
  constexpr int L = (C == 64) ? 64 : 32;
  const int lane = threadIdx.x & 63;
  const int ln = lane & (L - 1);
  const int wid = (blockIdx.x * blockDim.x + threadIdx.x) >> 6;
  const int v = (C == 64) ? wid : wid * 2 + (lane >> 5);
  if (v >= n) return;
  const float s = (LAYER == 1) ? 1.f : (LAYER == 2 ? sw[3] : sw[4]);
  const float fac = (LAYER == 1) ? 1.f : pinv[v];
  const float sf = s * fac;
  const int r0 = rowptr[v], r1 = rowptr[v + 1];
  const float av_d = adst[v], av_s = asrc[v];

  float rawsum = 0.f, den = 0.f;
  if (LAYER == 1) {
    for (int p = r0 + ln; p < r1; p += L) den += __int_as_float(edge[p].y);
  } else {
    for (int p = r0 + ln; p < r1; p += L) {
      int2 pk = edge[p];
      float a = __int_as_float(pk.y);
      rawsum += a;
      float lg = asrc[pk.x] + av_d + sf * a;
      float ex = __expf(LRELU(lg));
      edge[p].y = __float_as_int(ex);
      den += ex;
    }
    __threadfence_block();
  }
#pragma unroll
  for (int off = L / 2; off > 0; off >>= 1) {
    den += __shfl_xor(den, off);
    if (LAYER >= 2) rawsum += __shfl_xor(rawsum, off);
  }
  const float base = av_s + av_d;
  float la1 = 0.f, la2 = 0.f, e1 = 0.f, e2 = 0.f;
  if (LAYER >= 2) { la1 = fac * lp1[v]; e1 = __expf(LRELU(base + s * la1)); den += e1; }
  if (LAYER >= 3) { la2 = fac * lp2[v]; e2 = __expf(LRELU(base + s * la2)); den += e2; }
  int dd = (r1 - r0) + (LAYER - 1);
  if (dd < 1) dd = 1;
  float sum_a = (LAYER == 1) ? asum[v] : fac * rawsum + la1 + la2;
  float lmean = sum_a / (float)dd;
  float exm = __expf(LRELU(base + s * lmean));
  den += exm;
  float inv = 1.f / (den + 1e-16f);
  if (ln == 0) {
    if (LAYER < 3) oinv[v] = inv;
    if (LAYER == 1) ol1[v] = exm;
    if (LAYER == 2) { ol1[v] = e1; ol2[v] = exm; }
  }

  // pass B: serial over edges, lane = channel, 8-deep ILP, fp16 gathers
  const int c = ln;
  const __half* __restrict__ hc = h + c;
  float a0 = 0.f, a1 = 0.f, a2 = 0.f, a3 = 0.f;
  float a4 = 0.f, a5 = 0.f, a6 = 0.f, a7 = 0.f;
  int p = r0;
  for (; p + 8 <= r1; p += 8) {
    int2 k0 = edge[p],     k1 = edge[p + 1], k2 = edge[p + 2], k3 = edge[p + 3];
    int2 k4 = edge[p + 4], k5 = edge[p + 5], k6 = edge[p + 6], k7 = edge[p + 7];
    a0 += __int_as_float(k0.y) * __half2float(hc[(size_t)k0.x * C]);
    a1 += __int_as_float(k1.y) * __half2float(hc[(size_t)k1.x * C]);
    a2 += __int_as_float(k2.y) * __half2float(hc[(size_t)k2.x * C]);
    a3 += __int_as_float(k3.y) * __half2float(hc[(size_t)k3.x * C]);
    a4 += __int_as_float(k4.y) * __half2float(hc[(size_t)k4.x * C]);
    a5 += __int_as_float(k5.y) * __half2float(hc[(size_t)k5.x * C]);
    a6 += __int_as_float(k6.y) * __half2float(hc[(size_t)k6.x * C]);
    a7 += __int_as_float(k7.y) * __half2float(hc[(size_t)k7.x * C]);
  }
  for (; p < r1; ++p)
    a0 += __int_as_float(edge[p].y) * __half2float(hc[(size_t)edge[p].x * C]);
  float hv = __half2float(hc[(size_t)v * C]);
  float acc = ((a0 + a1) + (a2 + a3)) + ((a4 + a5) + (a6 + a7)) + (e1 + e2 + exm) * hv;
  float o = acc * inv + bias[c];
  if (LAYER < 3) o = fmaxf(o, 0.f);
  out[(size_t)v * C + c] = o;
}

// ---------------- global mean pool (block per graph) ----------------

__global__ void pool_k(const float* __restrict__ h, const int* __restrict__ batch,
                       float* __restrict__ out, int n) {
  int g = blockIdx.x;
  int lo = 0, hi = n;
  while (lo < hi) { int m = (lo + hi) >> 1; if (batch[m] < g) lo = m + 1; else hi = m; }
  int start = lo;
  hi = n;
  while (lo < hi) { int m = (lo + hi) >> 1; if (batch[m] < g + 1) lo = m + 1; else hi = m; }
  int end = lo;
  int t = threadIdx.x;
  int c = t & 31, r = t >> 5;
  float acc = 0.f;
  for (int v = start + r; v < end; v += 8) acc += h[(size_t)v * 32 + c];
  __shared__ float s[256];
  s[t] = acc;
  __syncthreads();
  if (t < 128) s[t] += s[t + 128];
  __syncthreads();
  if (t < 64) s[t] += s[t + 64];
  __syncthreads();
  if (t < 32) {
    float tot = s[t] + s[t + 32];
    int cnt = end - start;
    out[g * 32 + t] = tot / (float)(cnt > 0 ? cnt : 1);
  }
}

// ---------------- launch ----------------

extern "C" void kernel_launch(void* const* d_in, const int* in_sizes, int n_in,
                              void* d_out, int out_size, void* d_ws, size_t ws_size,
                              hipStream_t stream) {
  const float* x     = (const float*)d_in[0];
  const int*   ei    = (const int*)d_in[1];
  const float* eattr = (const float*)d_in[2];
  const int*   batch = (const int*)d_in[3];
  const float *W1 = (const float*)d_in[4],  *as1 = (const float*)d_in[5],
              *ad1 = (const float*)d_in[6], *We1 = (const float*)d_in[7],
              *ae1 = (const float*)d_in[8], *b1  = (const float*)d_in[9];
  const float *W2 = (const float*)d_in[10], *as2 = (const float*)d_in[11],
              *ad2 = (const float*)d_in[12], *We2 = (const float*)d_in[13],
              *ae2 = (const float*)d_in[14], *b2  = (const float*)d_in[15];
  const float *W3 = (const float*)d_in[16], *as3 = (const float*)d_in[17],
              *ad3 = (const float*)d_in[18], *We3 = (const float*)d_in[19],
              *ae3 = (const float*)d_in[20], *b3  = (const float*)d_in[21];

  const int n = in_sizes[3];
  const int E = in_sizes[1] / 2;
  const int G = out_size / 32;
  const int* srcp = ei;
  const int* dstp = ei + E;
  const int NSB = (n + SBN - 1) >> SBSH;  // super-buckets
  const int M = NSB * NB1;                // count-matrix entries

  char* w = (char*)d_ws;
  auto alloc = [&](size_t bytes) -> void* {
    void* p = (void*)w;
    w += (bytes + 255) & ~(size_t)255;
    return p;
  };
  int2*  recDS  = (int2*)alloc((size_t)E * 8);   // staging; aliased by O after sb_build
  float* recA   = (float*)alloc((size_t)E * 4);  // staging
  int2*  edge   = (int2*)alloc((size_t)E * 8);
  __half* H     = (__half*)alloc((size_t)n * 64 * 2);
  int*   gcnt   = (int*)alloc((size_t)M * 4);
  int*   gbase  = (int*)alloc((size_t)(M + 1) * 4);
  int*   rowptr = (int*)alloc((size_t)(n + 1) * 4);
  float* asum   = (float*)alloc((size_t)n * 4);
  float* asrcB  = (float*)alloc((size_t)n * 4);
  float* adstB  = (float*)alloc((size_t)n * 4);
  float* loopA  = (float*)alloc((size_t)n * 4);
  float* loopB1 = (float*)alloc((size_t)n * 4);
  float* loopB2 = (float*)alloc((size_t)n * 4);
  float* invA   = (float*)alloc((size_t)n * 4);
  float* invB   = (float*)alloc((size_t)n * 4);
  float* sw     = (float*)alloc(256);
  float* O      = (float*)recDS;  // alias: recDS dead after sb_build_k

  dim3 blk256(256);
  dim3 gWave((n + 3) / 4);
  const int nw3 = (n + 1) / 2;
  dim3 gWave3((nw3 + 3) / 4);

  small_weights_k<<<1, 64, 0, stream>>>(We1, ae1, We2, ae2, We3, ae3, sw);
  count1_k<<<NB1, blk256, 0, stream>>>(dstp, gcnt, E, NSB);
  scan_gbase_k<<<1, 1024, 0, stream>>>(gcnt, gbase, rowptr, M);
  append2_k<<<NB1, blk256, 0, stream>>>(srcp, dstp, eattr, gbase, recDS, recA, sw, E, NSB);
  gemm1_k<<<gWave, blk256, 0, stream>>>(x, W1, as1, ad1, H, asrcB, adstB, n);
  sb_build_k<<<NSB, 1024, 0, stream>>>(recDS, recA, gbase, asrcB, adstB,
                                       rowptr, asum, edge, n, NSB);
  // layer 1
  agg_k<1, 64><<<gWave, blk256, 0, stream>>>(rowptr, edge, H, asrcB, adstB, asum,
                                             nullptr, nullptr, nullptr,
                                             invA, loopA, nullptr, sw, b1, O, n);
  // layer 2
  gemm_tile_k<64><<<dim3((n + 63) / 64), blk256, 0, stream>>>(O, W2, as2, ad2, H, asrcB, adstB, n);
  agg_k<2, 64><<<gWave, blk256, 0, stream>>>(rowptr, edge, H, asrcB, adstB, nullptr,
                                             invA, loopA, nullptr,
                                             invB, loopB1, loopB2, sw, b2, O, n);
  // layer 3
  gemm_tile_k<32><<<dim3((n + 127) / 128), blk256, 0, stream>>>(O, W3, as3, ad3, H, asrcB, adstB, n);
  agg_k<3, 32><<<gWave3, blk256, 0, stream>>>(rowptr, edge, H, asrcB, adstB, nullptr,
                                              invB, loopB1, loopB2,
                                              nullptr, nullptr, nullptr, sw, b3, O, n);
  // pool
  pool_k<<<G, blk256, 0, stream>>>(O, batch, (float*)d_out, n);
}

// Round 7
// 500.745 us; speedup vs baseline: 1.8612x; 1.3018x over previous
//
#include <hip/hip_runtime.h>
#include <hip/hip_fp16.h>

#define LRELU(x) ((x) > 0.f ? (x) : 0.2f * (x))
#define SBSH 9      // 512 nodes per super-bucket
#define SBN 512
#define NB1 256     // blocks in count/append passes (each owns E/NB1 edges)
#define MAXSB 1024  // static LDS cap on super-bucket count
#define PC 16       // pool chunks per graph

// ---------------- small weights ----------------
// sw[0..2] = We1^T @ ae1 per edge-dim row; sw[3] = We2 . ae2; sw[4] = We3 . ae3
__global__ void small_weights_k(const float* __restrict__ We1, const float* __restrict__ ae1,
                                const float* __restrict__ We2, const float* __restrict__ ae2,
                                const float* __restrict__ We3, const float* __restrict__ ae3,
                                float* __restrict__ sw) {
  int t = threadIdx.x;  // 64 threads = 1 wave
  float v0 = We1[t] * ae1[t];
  float v1 = We1[64 + t] * ae1[t];
  float v2 = We1[128 + t] * ae1[t];
  float v3 = We2[t] * ae2[t];
  float v4 = (t < 32) ? We3[t] * ae3[t] : 0.f;
#pragma unroll
  for (int off = 32; off > 0; off >>= 1) {
    v0 += __shfl_down(v0, off);
    v1 += __shfl_down(v1, off);
    v2 += __shfl_down(v2, off);
    v3 += __shfl_down(v3, off);
    v4 += __shfl_down(v4, off);
  }
  if (t == 0) { sw[0] = v0; sw[1] = v1; sw[2] = v2; sw[3] = v3; sw[4] = v4; }
}

// ---------------- CSR build, atomic-free staging ----------------
// S1: per-(super-bucket, block) exact counts. Chunk per block fixed.
__global__ __launch_bounds__(256) void count1_k(const int* __restrict__ dst,
                                                int* __restrict__ gcnt, int E, int NSB) {
  __shared__ int cnt[MAXSB];
  const int t = threadIdx.x, blk = blockIdx.x;
  for (int i = t; i < NSB; i += 256) cnt[i] = 0;
  __syncthreads();
  const int CE = (E + NB1 - 1) / NB1;
  const int e0 = blk * CE, e1 = min(E, e0 + CE);
  for (int e = e0 + t; e < e1; e += 256) {
    int d = __builtin_nontemporal_load(&dst[e]);
    atomicAdd(&cnt[d >> SBSH], 1);
  }
  __syncthreads();
  for (int i = t; i < NSB; i += 256) gcnt[i * NB1 + blk] = cnt[i];  // sb-major
}

// S2a/b/c: hierarchical exclusive scan over M counters
__global__ __launch_bounds__(1024) void scanA_k(const int* __restrict__ gcnt,
                                                int* __restrict__ gbase,
                                                int* __restrict__ bsum, int M) {
  __shared__ int s[1024];
  const int t = threadIdx.x;
  const int i = blockIdx.x * 1024 + t;
  int v = (i < M) ? gcnt[i] : 0;
  s[t] = v;
  __syncthreads();
  for (int off = 1; off < 1024; off <<= 1) {
    int add = (t >= off) ? s[t - off] : 0;
    __syncthreads();
    s[t] += add;
    __syncthreads();
  }
  if (i < M) gbase[i] = s[t] - v;  // block-local exclusive
  if (t == 1023) bsum[blockIdx.x] = s[t];
}

__global__ void scanB_k(const int* __restrict__ bsum, int* __restrict__ boff, int nb) {
  if (threadIdx.x == 0) {
    int acc = 0;
    for (int b = 0; b < nb; b++) { boff[b] = acc; acc += bsum[b]; }
  }
}

__global__ void scanC_k(int* __restrict__ gbase, const int* __restrict__ boff,
                        int* __restrict__ rowptr, int M, int E) {
  int i = blockIdx.x * 256 + threadIdx.x;
  if (i < M) gbase[i] += boff[i >> 10];
  if (i == 0) { gbase[M] = E; rowptr[0] = 0; }
}

// S3: append into block-private reservations (LDS cursors, NO global atomics)
// rec = (loc 9b << 23) | src (23b)
__global__ __launch_bounds__(256) void append2_k(
    const int* __restrict__ src, const int* __restrict__ dst,
    const float* __restrict__ eattr, const int* __restrict__ gbase,
    unsigned int* __restrict__ recPK, float* __restrict__ recA,
    const float* __restrict__ sw, int E, int NSB) {
  __shared__ int base[MAXSB];
  __shared__ int off[MAXSB];
  const int t = threadIdx.x, blk = blockIdx.x;
  for (int i = t; i < NSB; i += 256) { base[i] = gbase[i * NB1 + blk]; off[i] = 0; }
  __syncthreads();
  const float w0 = sw[0], w1 = sw[1], w2 = sw[2];
  const int CE = (E + NB1 - 1) / NB1;
  const int e0 = blk * CE, e1 = min(E, e0 + CE);
  for (int e = e0 + t; e < e1; e += 256) {
    int d = __builtin_nontemporal_load(&dst[e]);
    int sv = __builtin_nontemporal_load(&src[e]);
    float a0 = __builtin_nontemporal_load(&eattr[e * 3]);
    float a1 = __builtin_nontemporal_load(&eattr[e * 3 + 1]);
    float a2 = __builtin_nontemporal_load(&eattr[e * 3 + 2]);
    float ae = a0 * w0 + a1 * w1 + a2 * w2;
    int sb = d >> SBSH;
    int pos = base[sb] + atomicAdd(&off[sb], 1);  // LDS atomic
    recPK[pos] = ((unsigned int)(d & (SBN - 1)) << 23) | (unsigned int)sv;
    recA[pos] = ae;
  }
}

// S4: one block per super-bucket: count 512 nodes, block-scan -> rowptr,
// place final edge[] = (src, layer-1 ex) into L2-local window; asum in LDS.
__global__ __launch_bounds__(1024) void sb_build_k(
    const unsigned int* __restrict__ recPK, const float* __restrict__ recA,
    const int* __restrict__ gbase, const float* __restrict__ asrc,
    const float* __restrict__ adst, int* __restrict__ rowptr,
    float* __restrict__ asum, int2* __restrict__ edge, int n, int NSB) {
  __shared__ int cnt[SBN];
  __shared__ int sc[SBN];
  __shared__ int fill[SBN];
  __shared__ float adl[SBN];
  __shared__ float rs[SBN];
  const int t = threadIdx.x, sb = blockIdx.x;
  const int v0 = sb << SBSH;
  const int nloc = min(SBN, n - v0);
  if (t < SBN) {
    cnt[t] = 0; fill[t] = 0; rs[t] = 0.f;
    adl[t] = (t < nloc) ? adst[v0 + t] : 0.f;
  }
  __syncthreads();
  const int seg0 = gbase[sb * NB1], seg1 = gbase[(sb + 1) * NB1];
  // pass 1: count
  for (int i = seg0 + t; i < seg1; i += 1024) atomicAdd(&cnt[recPK[i] >> 23], 1);
  __syncthreads();
  if (t < SBN) sc[t] = cnt[t];
  __syncthreads();
  // inclusive scan over 512 (all threads hit barriers)
  for (int off = 1; off < SBN; off <<= 1) {
    int add = (t < SBN && t >= off) ? sc[t - off] : 0;
    __syncthreads();
    if (t < SBN) sc[t] += add;
    __syncthreads();
  }
  if (t < nloc) rowptr[v0 + t + 1] = seg0 + sc[t];
  // pass 2: place + fused layer-1 exp + raw-attr sums
  for (int i = seg0 + t; i < seg1; i += 1024) {
    unsigned int q = recPK[i];
    float ae = recA[i];
    int loc = q >> 23;
    int sv = (int)(q & 0x7FFFFFu);
    int pos = seg0 + (sc[loc] - cnt[loc]) + atomicAdd(&fill[loc], 1);
    float ex = __expf(LRELU(asrc[sv] + adl[loc] + ae));
    edge[pos] = make_int2(sv, __float_as_int(ex));
    atomicAdd(&rs[loc], ae);
  }
  __syncthreads();
  if (t < nloc) asum[v0 + t] = rs[t];
}

// ---------------- layer-1 GEMM: x [n,5] @ W [5,64] (wave per node) -------------
// h stored fp16 (gather payload); asrc/adst from fp32 accumulators.

__global__ void gemm1_k(const float* __restrict__ x, const float* __restrict__ W,
                        const float* __restrict__ as, const float* __restrict__ ad,
                        __half* __restrict__ h, float* __restrict__ asrc,
                        float* __restrict__ adst, int n) {
  int lane = threadIdx.x & 63;
  int v = (blockIdx.x * blockDim.x + threadIdx.x) >> 6;
  if (v >= n) return;
  float acc = 0.f;
#pragma unroll
  for (int k = 0; k < 5; k++) acc += x[v * 5 + k] * W[k * 64 + lane];
  h[(size_t)v * 64 + lane] = __float2half(acc);
  float ps = acc * as[lane], pd = acc * ad[lane];
#pragma unroll
  for (int off = 32; off > 0; off >>= 1) {
    ps += __shfl_down(ps, off);
    pd += __shfl_down(pd, off);
  }
  if (lane == 0) { asrc[v] = ps; adst[v] = pd; }
}

// ---------------- tiled GEMM: x [n,64] @ W [64,C], 4x4 register blocking -------

template <int C>
__global__ __launch_bounds__(256) void gemm_tile_k(
    const float* __restrict__ x, const float* __restrict__ W,
    const float* __restrict__ as, const float* __restrict__ ad,
    __half* __restrict__ h, float* __restrict__ asrc, float* __restrict__ adst, int n) {
  constexpr int NT = 4096 / C;
  constexpr int CG = C / 4;
  constexpr int XTP = NT + 4;
  __shared__ float XT[64][XTP];
  __shared__ float Wl[64 * C];
  const int t = threadIdx.x;
  const int v0 = blockIdx.x * NT;
  for (int i = t; i < 64 * C; i += 256) Wl[i] = W[i];
  for (int i = t; i < NT * 64; i += 256) {
    int node = i >> 6, k = i & 63;
    int v = v0 + node;
    XT[k][node] = (v < n) ? x[(size_t)v * 64 + k] : 0.f;
  }
  __syncthreads();
  const int cg = t % CG, ng = t / CG;
  const int c0 = cg * 4, n0 = ng * 4;
  float acc[4][4] = {};
#pragma unroll 4
  for (int k = 0; k < 64; ++k) {
    const float4 xv = *(const float4*)&XT[k][n0];
    const float4 wv = *(const float4*)&Wl[k * C + c0];
    acc[0][0] += xv.x * wv.x; acc[0][1] += xv.x * wv.y; acc[0][2] += xv.x * wv.z; acc[0][3] += xv.x * wv.w;
    acc[1][0] += xv.y * wv.x; acc[1][1] += xv.y * wv.y; acc[1][2] += xv.y * wv.z; acc[1][3] += xv.y * wv.w;
    acc[2][0] += xv.z * wv.x; acc[2][1] += xv.z * wv.y; acc[2][2] += xv.z * wv.z; acc[2][3] += xv.z * wv.w;
    acc[3][0] += xv.w * wv.x; acc[3][1] += xv.w * wv.y; acc[3][2] += xv.w * wv.z; acc[3][3] += xv.w * wv.w;
  }
  float asv[4] = {as[c0], as[c0 + 1], as[c0 + 2], as[c0 + 3]};
  float adv[4] = {ad[c0], ad[c0 + 1], ad[c0 + 2], ad[c0 + 3]};
  float ps[4], pd[4];
#pragma unroll
  for (int ni = 0; ni < 4; ++ni) {
    ps[ni] = acc[ni][0] * asv[0] + acc[ni][1] * asv[1] + acc[ni][2] * asv[2] + acc[ni][3] * asv[3];
    pd[ni] = acc[ni][0] * adv[0] + acc[ni][1] * adv[1] + acc[ni][2] * adv[2] + acc[ni][3] * adv[3];
  }
#pragma unroll
  for (int off = CG / 2; off > 0; off >>= 1) {
#pragma unroll
    for (int ni = 0; ni < 4; ++ni) {
      ps[ni] += __shfl_xor(ps[ni], off);
      pd[ni] += __shfl_xor(pd[ni], off);
    }
  }
#pragma unroll
  for (int ni = 0; ni < 4; ++ni) {
    int v = v0 + n0 + ni;
    if (v < n) {
      union { __half hh[4]; uint2 u; } pk;
      pk.hh[0] = __float2half(acc[ni][0]);
      pk.hh[1] = __float2half(acc[ni][1]);
      pk.hh[2] = __float2half(acc[ni][2]);
      pk.hh[3] = __float2half(acc[ni][3]);
      *(uint2*)&h[(size_t)v * C + c0] = pk.u;
      if (cg == 0) { asrc[v] = ps[ni]; adst[v] = pd[ni]; }
    }
  }
}

// ---------------- per-node softmax + aggregate ----------------
// edge[p] = (src, ex). LAYER=1: ex precomputed by sb_build (read-only);
// raw attr sum in asum[]. LAYER>=2: ex field holds PREV layer's unnormalized
// ex; pass A replaces it in place. Deferred normalization via pinv/oinv.
// Pass B: edge-PAIRS, each half-group handles one edge via half2 gathers.
template <int LAYER, int C>
__global__ __launch_bounds__(256) void agg_k(
    const int* __restrict__ rowptr, int2* __restrict__ edge,
    const __half* __restrict__ h, const float* __restrict__ asrc,
    const float* __restrict__ adst, const float* __restrict__ asum,
    const float* __restrict__ pinv, const float* __restrict__ lp1,
    const float* __restrict__ lp2, float* __restrict__ oinv,
    float* __restrict__ ol1, float* __restrict__ ol2,
    const float* __restrict__ sw, const float* __restrict__ bias,
    float* __restrict__ out, int n) {
  constexpr int L = (C == 64) ? 64 : 32;   // lanes per node
  constexpr int EH = L / 2;                // lanes per edge in pass B
  constexpr int SH = (C == 64) ? 5 : 4;    // half2 row shift
  const int lane = threadIdx.x & 63;
  const int ln = lane & (L - 1);
  const int wid = (blockIdx.x * blockDim.x + threadIdx.x) >> 6;
  const int v = (C == 64) ? wid : wid * 2 + (lane >> 5);
  if (v >= n) return;
  const float s = (LAYER == 1) ? 1.f : (LAYER == 2 ? sw[3] : sw[4]);
  const float fac = (LAYER == 1) ? 1.f : pinv[v];
  const float sf = s * fac;
  const int r0 = rowptr[v], r1 = rowptr[v + 1];
  const float av_d = adst[v], av_s = asrc[v];

  // pass A (lane-parallel over edges)
  float rawsum = 0.f, den = 0.f;
  if (LAYER == 1) {
    for (int p = r0 + ln; p < r1; p += L) den += __int_as_float(edge[p].y);
  } else {
    for (int p = r0 + ln; p < r1; p += L) {
      int2 pk = edge[p];
      float a = __int_as_float(pk.y);
      rawsum += a;
      float lg = asrc[pk.x] + av_d + sf * a;
      float ex = __expf(LRELU(lg));
      edge[p].y = __float_as_int(ex);
      den += ex;
    }
    __threadfence_block();
  }
#pragma unroll
  for (int off = L / 2; off > 0; off >>= 1) {
    den += __shfl_xor(den, off);
    if (LAYER >= 2) rawsum += __shfl_xor(rawsum, off);
  }
  const float base = av_s + av_d;
  float la1 = 0.f, la2 = 0.f, e1 = 0.f, e2 = 0.f;
  if (LAYER >= 2) { la1 = fac * lp1[v]; e1 = __expf(LRELU(base + s * la1)); den += e1; }
  if (LAYER >= 3) { la2 = fac * lp2[v]; e2 = __expf(LRELU(base + s * la2)); den += e2; }
  int dd = (r1 - r0) + (LAYER - 1);
  if (dd < 1) dd = 1;
  float sum_a = (LAYER == 1) ? asum[v] : fac * rawsum + la1 + la2;
  float lmean = sum_a / (float)dd;
  float exm = __expf(LRELU(base + s * lmean));
  den += exm;
  float inv = 1.f / (den + 1e-16f);
  if (ln == 0) {
    if (LAYER < 3) oinv[v] = inv;
    if (LAYER == 1) ol1[v] = exm;
    if (LAYER == 2) { ol1[v] = e1; ol2[v] = exm; }
  }

  // pass B: edge pairs; half-group eo handles edge p+eo, lane covers 2 channels
  const int eo = ln >> (SH);            // wrong shift? EH=32->eo=ln>>5; EH=16->ln>>4
  const int cl = ln & (EH - 1);
  const __half2* __restrict__ h2 = (const __half2*)h;
  float2 a0 = {0.f, 0.f}, a1 = {0.f, 0.f}, a2 = {0.f, 0.f}, a3 = {0.f, 0.f};
  int p = r0;
  for (; p + 8 <= r1; p += 8) {
    int2 k0 = edge[p + eo];
    int2 k1 = edge[p + 2 + eo];
    int2 k2 = edge[p + 4 + eo];
    int2 k3 = edge[p + 6 + eo];
    float2 g0 = __half22float2(h2[(k0.x << SH) + cl]);
    float2 g1 = __half22float2(h2[(k1.x << SH) + cl]);
    float2 g2 = __half22float2(h2[(k2.x << SH) + cl]);
    float2 g3 = __half22float2(h2[(k3.x << SH) + cl]);
    float e0_ = __int_as_float(k0.y), e1_ = __int_as_float(k1.y);
    float e2_ = __int_as_float(k2.y), e3_ = __int_as_float(k3.y);
    a0.x += e0_ * g0.x; a0.y += e0_ * g0.y;
    a1.x += e1_ * g1.x; a1.y += e1_ * g1.y;
    a2.x += e2_ * g2.x; a2.y += e2_ * g2.y;
    a3.x += e3_ * g3.x; a3.y += e3_ * g3.y;
  }
  for (; p + 2 <= r1; p += 2) {
    int2 k = edge[p + eo];
    float2 g = __half22float2(h2[(k.x << SH) + cl]);
    float e_ = __int_as_float(k.y);
    a0.x += e_ * g.x; a0.y += e_ * g.y;
  }
  if (p < r1) {  // odd leftover: only eo==0 group contributes
    int2 k = edge[p];
    float2 g = __half22float2(h2[(k.x << SH) + cl]);
    float e_ = eo ? 0.f : __int_as_float(k.y);
    a0.x += e_ * g.x; a0.y += e_ * g.y;
  }
  float2 at;
  at.x = (a0.x + a1.x) + (a2.x + a3.x);
  at.y = (a0.y + a1.y) + (a2.y + a3.y);
  at.x += __shfl_xor(at.x, EH);
  at.y += __shfl_xor(at.y, EH);
  float2 hv = __half22float2(h2[(v << SH) + cl]);
  float sl = e1 + e2 + exm;
  float2 bi = *(const float2*)&bias[2 * cl];
  float ox = (at.x + sl * hv.x) * inv + bi.x;
  float oy = (at.y + sl * hv.y) * inv + bi.y;
  if (LAYER < 3) { ox = fmaxf(ox, 0.f); oy = fmaxf(oy, 0.f); }
  if (eo == 0) *(float2*)&out[(size_t)v * C + 2 * cl] = make_float2(ox, oy);
}

// ---------------- global mean pool, two-stage (deterministic) ----------------

__global__ __launch_bounds__(256) void poolA_k(const float* __restrict__ h,
                                               const int* __restrict__ batch,
                                               float* __restrict__ partial, int n) {
  const int b = blockIdx.x;
  const int g = b / PC, ch = b % PC;
  int lo = 0, hi = n;
  while (lo < hi) { int m = (lo + hi) >> 1; if (batch[m] < g) lo = m + 1; else hi = m; }
  const int start = lo;
  hi = n;
  while (lo < hi) { int m = (lo + hi) >> 1; if (batch[m] < g + 1) lo = m + 1; else hi = m; }
  const int end = lo;
  const int len = end - start;
  const int c0 = start + (int)((long long)len * ch / PC);
  const int c1 = start + (int)((long long)len * (ch + 1) / PC);
  const int t = threadIdx.x;
  const int c = t & 31, r = t >> 5;
  float acc = 0.f;
  for (int v = c0 + r; v < c1; v += 8) acc += h[(size_t)v * 32 + c];
  __shared__ float sm[256];
  sm[t] = acc;
  __syncthreads();
  if (t < 128) sm[t] += sm[t + 128];
  __syncthreads();
  if (t < 64) sm[t] += sm[t + 64];
  __syncthreads();
  if (t < 32) partial[(b << 5) + t] = sm[t] + sm[t + 32];
}

__global__ void poolB_k(const float* __restrict__ partial, const int* __restrict__ batch,
                        float* __restrict__ out, int n) {
  const int g = blockIdx.x;
  const int t = threadIdx.x;  // 64 threads, use 32
  if (t >= 32) return;
  int lo = 0, hi = n;
  while (lo < hi) { int m = (lo + hi) >> 1; if (batch[m] < g) lo = m + 1; else hi = m; }
  const int start = lo;
  hi = n;
  while (lo < hi) { int m = (lo + hi) >> 1; if (batch[m] < g + 1) lo = m + 1; else hi = m; }
  const int cnt = lo - start;
  float acc = 0.f;
#pragma unroll
  for (int ch = 0; ch < PC; ++ch) acc += partial[((g * PC + ch) << 5) + t];
  out[g * 32 + t] = acc / (float)(cnt > 0 ? cnt : 1);
}

// ---------------- launch ----------------

extern "C" void kernel_launch(void* const* d_in, const int* in_sizes, int n_in,
                              void* d_out, int out_size, void* d_ws, size_t ws_size,
                              hipStream_t stream) {
  const float* x     = (const float*)d_in[0];
  const int*   ei    = (const int*)d_in[1];
  const float* eattr = (const float*)d_in[2];
  const int*   batch = (const int*)d_in[3];
  const float *W1 = (const float*)d_in[4],  *as1 = (const float*)d_in[5],
              *ad1 = (const float*)d_in[6], *We1 = (const float*)d_in[7],
              *ae1 = (const float*)d_in[8], *b1  = (const float*)d_in[9];
  const float *W2 = (const float*)d_in[10], *as2 = (const float*)d_in[11],
              *ad2 = (const float*)d_in[12], *We2 = (const float*)d_in[13],
              *ae2 = (const float*)d_in[14], *b2  = (const float*)d_in[15];
  const float *W3 = (const float*)d_in[16], *as3 = (const float*)d_in[17],
              *ad3 = (const float*)d_in[18], *We3 = (const float*)d_in[19],
              *ae3 = (const float*)d_in[20], *b3  = (const float*)d_in[21];

  const int n = in_sizes[3];
  const int E = in_sizes[1] / 2;
  const int G = out_size / 32;
  const int* srcp = ei;
  const int* dstp = ei + E;
  const int NSB = (n + SBN - 1) >> SBSH;  // super-buckets
  const int M = NSB * NB1;                // count-matrix entries
  const int NBL = (M + 1023) / 1024;      // scan blocks

  char* w = (char*)d_ws;
  auto alloc = [&](size_t bytes) -> void* {
    void* p = (void*)w;
    w += (bytes + 255) & ~(size_t)255;
    return p;
  };
  // staging blob (recPK | recA), aliased by O after sb_build
  size_t eb = ((size_t)E * 4 + 255) & ~(size_t)255;
  char* blob = (char*)alloc(eb * 2 > (size_t)n * 256 ? eb * 2 : (size_t)n * 256);
  unsigned int* recPK = (unsigned int*)blob;
  float* recA  = (float*)(blob + eb);
  float* O     = (float*)blob;           // alias: staging dead after sb_build_k
  int2*  edge  = (int2*)alloc((size_t)E * 8);
  __half* H    = (__half*)alloc((size_t)n * 64 * 2);
  int*   gcnt  = (int*)alloc((size_t)M * 4);
  int*   gbase = (int*)alloc((size_t)(M + 1) * 4);
  int*   bsum  = (int*)alloc((size_t)NBL * 4 + 256);
  int*   boff  = (int*)alloc((size_t)NBL * 4 + 256);
  int*   rowptr= (int*)alloc((size_t)(n + 1) * 4);
  float* asum  = (float*)alloc((size_t)n * 4);
  float* asrcB = (float*)alloc((size_t)n * 4);
  float* adstB = (float*)alloc((size_t)n * 4);
  float* loopA = (float*)alloc((size_t)n * 4);
  float* loopB1= (float*)alloc((size_t)n * 4);
  float* loopB2= (float*)alloc((size_t)n * 4);
  float* invA  = (float*)alloc((size_t)n * 4);
  float* invB  = (float*)alloc((size_t)n * 4);
  float* sw    = (float*)alloc(256);
  float* part  = (float*)alloc((size_t)G * PC * 32 * 4);

  dim3 blk256(256);
  dim3 gWave((n + 3) / 4);
  const int nw3 = (n + 1) / 2;
  dim3 gWave3((nw3 + 3) / 4);

  small_weights_k<<<1, 64, 0, stream>>>(We1, ae1, We2, ae2, We3, ae3, sw);
  count1_k<<<NB1, blk256, 0, stream>>>(dstp, gcnt, E, NSB);
  scanA_k<<<NBL, 1024, 0, stream>>>(gcnt, gbase, bsum, M);
  scanB_k<<<1, 64, 0, stream>>>(bsum, boff, NBL);
  scanC_k<<<dim3((M + 256) / 256), blk256, 0, stream>>>(gbase, boff, rowptr, M, E);
  append2_k<<<NB1, blk256, 0, stream>>>(srcp, dstp, eattr, gbase, recPK, recA, sw, E, NSB);
  gemm1_k<<<gWave, blk256, 0, stream>>>(x, W1, as1, ad1, H, asrcB, adstB, n);
  sb_build_k<<<NSB, 1024, 0, stream>>>(recPK, recA, gbase, asrcB, adstB,
                                       rowptr, asum, edge, n, NSB);
  // layer 1
  agg_k<1, 64><<<gWave, blk256, 0, stream>>>(rowptr, edge, H, asrcB, adstB, asum,
                                             nullptr, nullptr, nullptr,
                                             invA, loopA, nullptr, sw, b1, O, n);
  // layer 2
  gemm_tile_k<64><<<dim3((n + 63) / 64), blk256, 0, stream>>>(O, W2, as2, ad2, H, asrcB, adstB, n);
  agg_k<2, 64><<<gWave, blk256, 0, stream>>>(rowptr, edge, H, asrcB, adstB, nullptr,
                                             invA, loopA, nullptr,
                                             invB, loopB1, loopB2, sw, b2, O, n);
  // layer 3
  gemm_tile_k<32><<<dim3((n + 127) / 128), blk256, 0, stream>>>(O, W3, as3, ad3, H, asrcB, adstB, n);
  agg_k<3, 32><<<gWave3, blk256, 0, stream>>>(rowptr, edge, H, asrcB, adstB, nullptr,
                                              invB, loopB1, loopB2,
                                              nullptr, nullptr, nullptr, sw, b3, O, n);
  // pool
  poolA_k<<<dim3(G * PC), blk256, 0, stream>>>(O, batch, part, n);
  poolB_k<<<G, 64, 0, stream>>>(part, batch, (float*)d_out, n);
}